// Round 4
// baseline (820.822 us; speedup 1.0000x reference)
//
#include <hip/hip_runtime.h>
#include <hip/hip_bf16.h>

#define N_FEAT 128
#define N_HID  128
#define N_CLASS 40

// ---------------------------------------------------------------------------
// CSR build: count degrees
// ---------------------------------------------------------------------------
__global__ void k_count(const int* __restrict__ dst, int* __restrict__ cnt, int E) {
    int e = blockIdx.x * blockDim.x + threadIdx.x;
    if (e < E) atomicAdd(&cnt[dst[e]], 1);
}

// ---------------------------------------------------------------------------
// Single-block exclusive prefix scan over cnt[0..n) -> off[0..n], cur copy.
// ---------------------------------------------------------------------------
__global__ __launch_bounds__(1024) void k_scan(const int* __restrict__ cnt,
                                               int* __restrict__ off,
                                               int* __restrict__ cur, int n) {
    const int tid = threadIdx.x;
    const int lane = tid & 63;
    const int wid = tid >> 6;              // 16 waves
    __shared__ int wsum[16];
    __shared__ int carry;
    if (tid == 0) carry = 0;
    __syncthreads();
    for (int base = 0; base < n; base += 1024) {
        int i = base + tid;
        int v = (i < n) ? cnt[i] : 0;
        int inc = v;
        #pragma unroll
        for (int s = 1; s < 64; s <<= 1) {
            int t = __shfl_up(inc, s);
            if (lane >= s) inc += t;
        }
        if (lane == 63) wsum[wid] = inc;
        __syncthreads();
        if (wid == 0) {
            int w = (lane < 16) ? wsum[lane] : 0;
            #pragma unroll
            for (int s = 1; s < 16; s <<= 1) {
                int t = __shfl_up(w, s);
                if (lane >= s) w += t;
            }
            if (lane < 16) wsum[lane] = w;  // inclusive wave sums
        }
        __syncthreads();
        int wbase = (wid > 0) ? wsum[wid - 1] : 0;
        int exc = carry + wbase + inc - v;  // exclusive prefix
        if (i < n) { off[i] = exc; cur[i] = exc; }
        int chunk_total = wsum[15];
        __syncthreads();
        if (tid == 0) carry += chunk_total;
        __syncthreads();
    }
    if (tid == 0) off[n] = carry;           // == E
}

// ---------------------------------------------------------------------------
// CSR build: scatter src ids into per-dst buckets
// ---------------------------------------------------------------------------
__global__ void k_fill(const int* __restrict__ src, const int* __restrict__ dst,
                       int* __restrict__ cur, int* __restrict__ srt, int E) {
    int e = blockIdx.x * blockDim.x + threadIdx.x;
    if (e < E) {
        int p = atomicAdd(&cur[dst[e]], 1);
        srt[p] = src[e];
    }
}

// ---------------------------------------------------------------------------
// Mean aggregation: one wave per node, lane holds 2 features (float2).
// ---------------------------------------------------------------------------
__global__ __launch_bounds__(256) void k_agg(const float* __restrict__ feat,
                                             const int* __restrict__ srt,
                                             const int* __restrict__ off,
                                             const int* __restrict__ cnt,
                                             float* __restrict__ out, int n_nodes) {
    int wave = (blockIdx.x * blockDim.x + threadIdx.x) >> 6;
    int lane = threadIdx.x & 63;
    if (wave >= n_nodes) return;
    int beg = off[wave];
    int end = off[wave + 1];
    float2 acc = make_float2(0.f, 0.f);
    for (int e = beg; e < end; ++e) {
        int s = srt[e];
        const float2* row = (const float2*)(feat + (size_t)s * N_FEAT);
        float2 v = row[lane];
        acc.x += v.x;
        acc.y += v.y;
    }
    int c = cnt[wave];
    float inv = 1.0f / (float)(c > 1 ? c : 1);
    acc.x *= inv;
    acc.y *= inv;
    ((float2*)(out + (size_t)wave * N_FEAT))[lane] = acc;
}

// ---------------------------------------------------------------------------
// GEMM layer 1: h = relu(agg@Wl + x@Wr + b).
// Structure (R3 post-mortem: thread-per-node spilled accs / thrashed I$):
//   wave = 16 nodes x 128 cols; lane owns cols {2*lane, 2*lane+1}.
//   Weights  -> coalesced float2 vector loads (lane-consecutive, L1/L2-hot).
//   Activations -> wave-uniform scalar loads (nb readfirstlane'd) -> s_load.
//   16 named float2 accs/lane; k-loop unroll 2 only (I$-resident body).
//   No column split: every activation row is read exactly once.
// ---------------------------------------------------------------------------
__global__ __launch_bounds__(256, 4) void k_gemm1(const float* __restrict__ agg,
                                                  const float* __restrict__ x,
                                                  const float* __restrict__ Wl,
                                                  const float* __restrict__ Wr,
                                                  const float* __restrict__ b,
                                                  float* __restrict__ h, int n_nodes) {
    int wave = (int)((blockIdx.x * 256 + threadIdx.x) >> 6);
    wave = __builtin_amdgcn_readfirstlane(wave);
    int lane = threadIdx.x & 63;
    int nb = wave * 16;
    if (nb >= n_nodes) return;                    // uniform branch
    int c2 = lane * 2;

    float2 bias = *(const float2*)(b + c2);
    float2 A0 = bias, A1 = bias, A2 = bias, A3 = bias,
           A4 = bias, A5 = bias, A6 = bias, A7 = bias,
           A8 = bias, A9 = bias, A10 = bias, A11 = bias,
           A12 = bias, A13 = bias, A14 = bias, A15 = bias;

    const float* ap = agg + (size_t)nb * N_FEAT;  // uniform base
    const float* xp = x + (size_t)nb * N_FEAT;    // uniform base
    const float* wlp = Wl + c2;
    const float* wrp = Wr + c2;

    #pragma unroll 2
    for (int k = 0; k < N_FEAT; ++k) {
        float2 wl2 = *(const float2*)(wlp + (size_t)k * N_HID);
        float2 wr2 = *(const float2*)(wrp + (size_t)k * N_HID);
        #define STEP1(J, ACC) { \
            float av = ap[(J) * N_FEAT + k]; \
            float xv = xp[(J) * N_FEAT + k]; \
            ACC.x = fmaf(av, wl2.x, fmaf(xv, wr2.x, ACC.x)); \
            ACC.y = fmaf(av, wl2.y, fmaf(xv, wr2.y, ACC.y)); }
        STEP1(0, A0)   STEP1(1, A1)   STEP1(2, A2)   STEP1(3, A3)
        STEP1(4, A4)   STEP1(5, A5)   STEP1(6, A6)   STEP1(7, A7)
        STEP1(8, A8)   STEP1(9, A9)   STEP1(10, A10) STEP1(11, A11)
        STEP1(12, A12) STEP1(13, A13) STEP1(14, A14) STEP1(15, A15)
        #undef STEP1
    }

    #define STORE1(J, ACC) { \
        float2 o; o.x = fmaxf(ACC.x, 0.f); o.y = fmaxf(ACC.y, 0.f); \
        *(float2*)(h + (size_t)(nb + (J)) * N_HID + c2) = o; }
    STORE1(0, A0)   STORE1(1, A1)   STORE1(2, A2)   STORE1(3, A3)
    STORE1(4, A4)   STORE1(5, A5)   STORE1(6, A6)   STORE1(7, A7)
    STORE1(8, A8)   STORE1(9, A9)   STORE1(10, A10) STORE1(11, A11)
    STORE1(12, A12) STORE1(13, A13) STORE1(14, A14) STORE1(15, A15)
    #undef STORE1
}

// ---------------------------------------------------------------------------
// GEMM layer 2: out = agg2@Wl2 + h@Wr2 + b2. Same structure; lane = col
// (lanes >= 40 compute on clamped col 0 and don't store).
// ---------------------------------------------------------------------------
__global__ __launch_bounds__(256, 4) void k_gemm2(const float* __restrict__ agg2,
                                                  const float* __restrict__ h,
                                                  const float* __restrict__ Wl,
                                                  const float* __restrict__ Wr,
                                                  const float* __restrict__ b,
                                                  float* __restrict__ outp, int n_nodes) {
    int wave = (int)((blockIdx.x * 256 + threadIdx.x) >> 6);
    wave = __builtin_amdgcn_readfirstlane(wave);
    int lane = threadIdx.x & 63;
    int nb = wave * 16;
    if (nb >= n_nodes) return;                    // uniform branch
    bool active = lane < N_CLASS;
    int c = active ? lane : 0;

    float bias = b[c];
    float A0 = bias, A1 = bias, A2 = bias, A3 = bias,
          A4 = bias, A5 = bias, A6 = bias, A7 = bias,
          A8 = bias, A9 = bias, A10 = bias, A11 = bias,
          A12 = bias, A13 = bias, A14 = bias, A15 = bias;

    const float* ap = agg2 + (size_t)nb * N_HID;  // uniform base
    const float* hp = h + (size_t)nb * N_HID;     // uniform base
    const float* wlp = Wl + c;
    const float* wrp = Wr + c;

    #pragma unroll 2
    for (int k = 0; k < N_HID; ++k) {
        float wlv = wlp[(size_t)k * N_CLASS];
        float wrv = wrp[(size_t)k * N_CLASS];
        #define STEP2(J, ACC) { \
            float av = ap[(J) * N_HID + k]; \
            float hv = hp[(J) * N_HID + k]; \
            ACC = fmaf(av, wlv, fmaf(hv, wrv, ACC)); }
        STEP2(0, A0)   STEP2(1, A1)   STEP2(2, A2)   STEP2(3, A3)
        STEP2(4, A4)   STEP2(5, A5)   STEP2(6, A6)   STEP2(7, A7)
        STEP2(8, A8)   STEP2(9, A9)   STEP2(10, A10) STEP2(11, A11)
        STEP2(12, A12) STEP2(13, A13) STEP2(14, A14) STEP2(15, A15)
        #undef STEP2
    }

    if (active) {
        #define STORE2(J, ACC) outp[(size_t)(nb + (J)) * N_CLASS + lane] = ACC;
        STORE2(0, A0)   STORE2(1, A1)   STORE2(2, A2)   STORE2(3, A3)
        STORE2(4, A4)   STORE2(5, A5)   STORE2(6, A6)   STORE2(7, A7)
        STORE2(8, A8)   STORE2(9, A9)   STORE2(10, A10) STORE2(11, A11)
        STORE2(12, A12) STORE2(13, A13) STORE2(14, A14) STORE2(15, A15)
        #undef STORE2
    }
}

extern "C" void kernel_launch(void* const* d_in, const int* in_sizes, int n_in,
                              void* d_out, int out_size, void* d_ws, size_t ws_size,
                              hipStream_t stream) {
    const float* x   = (const float*)d_in[0];
    const int*   ei  = (const int*)d_in[1];   // [2][E] int32: row0=src, row1=dst
    const float* Wl1 = (const float*)d_in[2];
    const float* Wr1 = (const float*)d_in[3];
    const float* b1  = (const float*)d_in[4];
    const float* Wl2 = (const float*)d_in[5];
    const float* Wr2 = (const float*)d_in[6];
    const float* b2  = (const float*)d_in[7];
    float* out = (float*)d_out;

    const int N = in_sizes[0] / N_FEAT;       // 50000
    const int E = in_sizes[1] / 2;            // 800000
    const int* src = ei;
    const int* dst = ei + E;

    float* agg = (float*)d_ws;                       // N*128 fp32 (reused for agg2)
    float* h   = agg + (size_t)N * N_FEAT;           // N*128 fp32
    int*   cnt = (int*)(h + (size_t)N * N_HID);      // N
    int*   off = cnt + N;                            // N+1
    int*   cur = off + N + 1;                        // N
    int*   srt = cur + N;                            // E

    hipMemsetAsync(cnt, 0, (size_t)N * sizeof(int), stream);

    const int TB = 256;
    int eblocks = (E + TB - 1) / TB;
    k_count<<<eblocks, TB, 0, stream>>>(dst, cnt, E);
    k_scan<<<1, 1024, 0, stream>>>(cnt, off, cur, N);
    k_fill<<<eblocks, TB, 0, stream>>>(src, dst, cur, srt, E);

    int aggblocks = (N * 64 + TB - 1) / TB;   // one wave (64 lanes) per node
    int gblocks = (N + 63) / 64;              // 4 waves/block x 16 nodes/wave

    // Layer 1
    k_agg<<<aggblocks, TB, 0, stream>>>(x, srt, off, cnt, agg, N);
    k_gemm1<<<gblocks, TB, 0, stream>>>(agg, x, Wl1, Wr1, b1, h, N);

    // Layer 2
    k_agg<<<aggblocks, TB, 0, stream>>>(h, srt, off, cnt, agg, N);
    k_gemm2<<<gblocks, TB, 0, stream>>>(agg, h, Wl2, Wr2, b2, out, N);
}

// Round 5
// 364.602 us; speedup vs baseline: 2.2513x; 2.2513x over previous
//
#include <hip/hip_runtime.h>
#include <hip/hip_bf16.h>

#define N_FEAT 128
#define N_HID  128
#define N_CLASS 40

typedef __attribute__((ext_vector_type(8))) __bf16 bf16x8;
typedef __attribute__((ext_vector_type(4))) float f32x4;

__device__ __forceinline__ unsigned short f2bf(float f) {
    union { float f; unsigned int u; } v; v.f = f;
    unsigned int r = (v.u + 0x7FFFu + ((v.u >> 16) & 1u)) >> 16;
    return (unsigned short)r;
}
__device__ __forceinline__ float bf2f_lo(unsigned int p) {   // low ushort -> float
    union { unsigned int u; float f; } v; v.u = p << 16; return v.f;
}
__device__ __forceinline__ float bf2f_hi(unsigned int p) {   // high ushort -> float
    union { unsigned int u; float f; } v; v.u = p & 0xFFFF0000u; return v.f;
}

// ---------------------------------------------------------------------------
// CSR build: count degrees
// ---------------------------------------------------------------------------
__global__ void k_count(const int* __restrict__ dst, int* __restrict__ cnt, int E) {
    int e = blockIdx.x * blockDim.x + threadIdx.x;
    if (e < E) atomicAdd(&cnt[dst[e]], 1);
}

// ---------------------------------------------------------------------------
// Single-block exclusive prefix scan over cnt[0..n) -> off[0..n], cur copy.
// ---------------------------------------------------------------------------
__global__ __launch_bounds__(1024) void k_scan(const int* __restrict__ cnt,
                                               int* __restrict__ off,
                                               int* __restrict__ cur, int n) {
    const int tid = threadIdx.x;
    const int lane = tid & 63;
    const int wid = tid >> 6;              // 16 waves
    __shared__ int wsum[16];
    __shared__ int carry;
    if (tid == 0) carry = 0;
    __syncthreads();
    for (int base = 0; base < n; base += 1024) {
        int i = base + tid;
        int v = (i < n) ? cnt[i] : 0;
        int inc = v;
        #pragma unroll
        for (int s = 1; s < 64; s <<= 1) {
            int t = __shfl_up(inc, s);
            if (lane >= s) inc += t;
        }
        if (lane == 63) wsum[wid] = inc;
        __syncthreads();
        if (wid == 0) {
            int w = (lane < 16) ? wsum[lane] : 0;
            #pragma unroll
            for (int s = 1; s < 16; s <<= 1) {
                int t = __shfl_up(w, s);
                if (lane >= s) w += t;
            }
            if (lane < 16) wsum[lane] = w;  // inclusive wave sums
        }
        __syncthreads();
        int wbase = (wid > 0) ? wsum[wid - 1] : 0;
        int exc = carry + wbase + inc - v;  // exclusive prefix
        if (i < n) { off[i] = exc; cur[i] = exc; }
        int chunk_total = wsum[15];
        __syncthreads();
        if (tid == 0) carry += chunk_total;
        __syncthreads();
    }
    if (tid == 0) off[n] = carry;           // == E
}

// ---------------------------------------------------------------------------
// CSR build: scatter src ids into per-dst buckets
// ---------------------------------------------------------------------------
__global__ void k_fill(const int* __restrict__ src, const int* __restrict__ dst,
                       int* __restrict__ cur, int* __restrict__ srt, int E) {
    int e = blockIdx.x * blockDim.x + threadIdx.x;
    if (e < E) {
        int p = atomicAdd(&cur[dst[e]], 1);
        srt[p] = src[e];
    }
}

// ---------------------------------------------------------------------------
// fp32 -> bf16 bulk convert (n multiple of 4)
// ---------------------------------------------------------------------------
__global__ void k_cvt(const float* __restrict__ in, unsigned short* __restrict__ outp, int n) {
    int i = (blockIdx.x * 256 + threadIdx.x) * 4;
    if (i >= n) return;
    float4 v = *(const float4*)(in + i);
    ushort4 o;
    o.x = f2bf(v.x); o.y = f2bf(v.y); o.z = f2bf(v.z); o.w = f2bf(v.w);
    *(ushort4*)(outp + i) = o;
}

// ---------------------------------------------------------------------------
// Weight swizzle into MFMA B-fragment order (bf16).
// B-frag for 16x16x32: lane holds B[kc*32 + (lane>>4)*8 + j][ct*16 + (lane&15)].
// Stored so a lane's 8 elements are contiguous: sw[((ct*4+kc)*64 + lane)*8 + j].
// Cols >= ncols are zero-padded (gemm2: 40 cols -> 3 tiles of 16).
// ---------------------------------------------------------------------------
__global__ void k_swz(const float* __restrict__ W, unsigned short* __restrict__ sw,
                      int ncols, int nt) {
    int t = blockIdx.x * 256 + threadIdx.x;
    if (t >= nt * 4 * 64) return;
    int lane = t & 63;
    int bi = t >> 6;
    int kc = bi & 3, ct = bi >> 2;
    int n = lane & 15, q = lane >> 4;
    int col = ct * 16 + n;
    #pragma unroll
    for (int j = 0; j < 8; ++j) {
        int k = kc * 32 + q * 8 + j;
        float f = (col < ncols) ? W[(size_t)k * ncols + col] : 0.f;
        sw[(size_t)t * 8 + j] = f2bf(f);
    }
}

// ---------------------------------------------------------------------------
// Mean aggregation over bf16 features: one wave per node, lane holds 2 cols
// (one dword). fp32 accumulate, bf16 output.
// ---------------------------------------------------------------------------
__global__ __launch_bounds__(256) void k_aggb(const unsigned short* __restrict__ feat,
                                              const int* __restrict__ srt,
                                              const int* __restrict__ off,
                                              const int* __restrict__ cnt,
                                              unsigned short* __restrict__ outp, int n_nodes) {
    int wave = (blockIdx.x * blockDim.x + threadIdx.x) >> 6;
    int lane = threadIdx.x & 63;
    if (wave >= n_nodes) return;
    int beg = off[wave];
    int end = off[wave + 1];
    float ax = 0.f, ay = 0.f;
    #pragma unroll 2
    for (int e = beg; e < end; ++e) {
        int s = srt[e];
        unsigned int p = *(const unsigned int*)(feat + (size_t)s * N_FEAT + lane * 2);
        ax += bf2f_lo(p);
        ay += bf2f_hi(p);
    }
    int c = cnt[wave];
    float inv = 1.0f / (float)(c > 1 ? c : 1);
    unsigned int o = ((unsigned int)f2bf(ay * inv) << 16) | f2bf(ax * inv);
    *(unsigned int*)(outp + (size_t)wave * N_FEAT + lane * 2) = o;
}

// ---------------------------------------------------------------------------
// GEMM1 via MFMA 16x16x32 bf16: h = relu(agg@Wl + x@Wr + b), bf16 out.
// Wave = 16 nodes x 128 cols. A-frags: lane reads 8 contiguous bf16 from
// row-major activations (A[m=lane&15][k=(lane>>4)*8+j]). B pre-swizzled.
// C/D layout: col=lane&15, row=(lane>>4)*4+reg (measured m89/m91).
// ---------------------------------------------------------------------------
__global__ __launch_bounds__(256) void k_gemm1m(const unsigned short* __restrict__ aggb,
                                                const unsigned short* __restrict__ xb,
                                                const unsigned short* __restrict__ Bl,
                                                const unsigned short* __restrict__ Br,
                                                const float* __restrict__ bias,
                                                unsigned short* __restrict__ hb, int n_nodes) {
    int wid = (blockIdx.x * 256 + threadIdx.x) >> 6;
    int lane = threadIdx.x & 63;
    int nb = wid * 16;
    if (nb >= n_nodes) return;                 // wave-uniform
    int m = lane & 15, q = lane >> 4;
    size_t abase = (size_t)(nb + m) * N_FEAT + q * 8;
    bf16x8 Aa0 = *(const bf16x8*)(aggb + abase);
    bf16x8 Aa1 = *(const bf16x8*)(aggb + abase + 32);
    bf16x8 Aa2 = *(const bf16x8*)(aggb + abase + 64);
    bf16x8 Aa3 = *(const bf16x8*)(aggb + abase + 96);
    bf16x8 Ax0 = *(const bf16x8*)(xb + abase);
    bf16x8 Ax1 = *(const bf16x8*)(xb + abase + 32);
    bf16x8 Ax2 = *(const bf16x8*)(xb + abase + 64);
    bf16x8 Ax3 = *(const bf16x8*)(xb + abase + 96);
    const bf16x8* blp = (const bf16x8*)Bl + lane;
    const bf16x8* brp = (const bf16x8*)Br + lane;

    #pragma unroll
    for (int ct = 0; ct < 8; ++ct) {
        f32x4 acc = {0.f, 0.f, 0.f, 0.f};
        acc = __builtin_amdgcn_mfma_f32_16x16x32_bf16(Aa0, blp[(ct*4+0)*64], acc, 0,0,0);
        acc = __builtin_amdgcn_mfma_f32_16x16x32_bf16(Ax0, brp[(ct*4+0)*64], acc, 0,0,0);
        acc = __builtin_amdgcn_mfma_f32_16x16x32_bf16(Aa1, blp[(ct*4+1)*64], acc, 0,0,0);
        acc = __builtin_amdgcn_mfma_f32_16x16x32_bf16(Ax1, brp[(ct*4+1)*64], acc, 0,0,0);
        acc = __builtin_amdgcn_mfma_f32_16x16x32_bf16(Aa2, blp[(ct*4+2)*64], acc, 0,0,0);
        acc = __builtin_amdgcn_mfma_f32_16x16x32_bf16(Ax2, brp[(ct*4+2)*64], acc, 0,0,0);
        acc = __builtin_amdgcn_mfma_f32_16x16x32_bf16(Aa3, blp[(ct*4+3)*64], acc, 0,0,0);
        acc = __builtin_amdgcn_mfma_f32_16x16x32_bf16(Ax3, brp[(ct*4+3)*64], acc, 0,0,0);
        int col = ct * 16 + m;
        float bv = bias[col];
        hb[(size_t)(nb + q*4 + 0) * N_HID + col] = f2bf(fmaxf(acc.x + bv, 0.f));
        hb[(size_t)(nb + q*4 + 1) * N_HID + col] = f2bf(fmaxf(acc.y + bv, 0.f));
        hb[(size_t)(nb + q*4 + 2) * N_HID + col] = f2bf(fmaxf(acc.z + bv, 0.f));
        hb[(size_t)(nb + q*4 + 3) * N_HID + col] = f2bf(fmaxf(acc.w + bv, 0.f));
    }
}

// ---------------------------------------------------------------------------
// GEMM2 via MFMA: out = agg2@Wl2 + h@Wr2 + b2, fp32 out, 40 cols (3 tiles,
// last half-masked).
// ---------------------------------------------------------------------------
__global__ __launch_bounds__(256) void k_gemm2m(const unsigned short* __restrict__ aggb,
                                                const unsigned short* __restrict__ hb,
                                                const unsigned short* __restrict__ Bl,
                                                const unsigned short* __restrict__ Br,
                                                const float* __restrict__ bias,
                                                float* __restrict__ outp, int n_nodes) {
    int wid = (blockIdx.x * 256 + threadIdx.x) >> 6;
    int lane = threadIdx.x & 63;
    int nb = wid * 16;
    if (nb >= n_nodes) return;                 // wave-uniform
    int m = lane & 15, q = lane >> 4;
    size_t abase = (size_t)(nb + m) * N_HID + q * 8;
    bf16x8 Aa0 = *(const bf16x8*)(aggb + abase);
    bf16x8 Aa1 = *(const bf16x8*)(aggb + abase + 32);
    bf16x8 Aa2 = *(const bf16x8*)(aggb + abase + 64);
    bf16x8 Aa3 = *(const bf16x8*)(aggb + abase + 96);
    bf16x8 Ah0 = *(const bf16x8*)(hb + abase);
    bf16x8 Ah1 = *(const bf16x8*)(hb + abase + 32);
    bf16x8 Ah2 = *(const bf16x8*)(hb + abase + 64);
    bf16x8 Ah3 = *(const bf16x8*)(hb + abase + 96);
    const bf16x8* blp = (const bf16x8*)Bl + lane;
    const bf16x8* brp = (const bf16x8*)Br + lane;

    #pragma unroll
    for (int ct = 0; ct < 3; ++ct) {
        f32x4 acc = {0.f, 0.f, 0.f, 0.f};
        acc = __builtin_amdgcn_mfma_f32_16x16x32_bf16(Aa0, blp[(ct*4+0)*64], acc, 0,0,0);
        acc = __builtin_amdgcn_mfma_f32_16x16x32_bf16(Ah0, brp[(ct*4+0)*64], acc, 0,0,0);
        acc = __builtin_amdgcn_mfma_f32_16x16x32_bf16(Aa1, blp[(ct*4+1)*64], acc, 0,0,0);
        acc = __builtin_amdgcn_mfma_f32_16x16x32_bf16(Ah1, brp[(ct*4+1)*64], acc, 0,0,0);
        acc = __builtin_amdgcn_mfma_f32_16x16x32_bf16(Aa2, blp[(ct*4+2)*64], acc, 0,0,0);
        acc = __builtin_amdgcn_mfma_f32_16x16x32_bf16(Ah2, brp[(ct*4+2)*64], acc, 0,0,0);
        acc = __builtin_amdgcn_mfma_f32_16x16x32_bf16(Aa3, blp[(ct*4+3)*64], acc, 0,0,0);
        acc = __builtin_amdgcn_mfma_f32_16x16x32_bf16(Ah3, brp[(ct*4+3)*64], acc, 0,0,0);
        int col = ct * 16 + m;
        if (col < N_CLASS) {
            float bv = bias[col];
            outp[(size_t)(nb + q*4 + 0) * N_CLASS + col] = acc.x + bv;
            outp[(size_t)(nb + q*4 + 1) * N_CLASS + col] = acc.y + bv;
            outp[(size_t)(nb + q*4 + 2) * N_CLASS + col] = acc.z + bv;
            outp[(size_t)(nb + q*4 + 3) * N_CLASS + col] = acc.w + bv;
        }
    }
}

extern "C" void kernel_launch(void* const* d_in, const int* in_sizes, int n_in,
                              void* d_out, int out_size, void* d_ws, size_t ws_size,
                              hipStream_t stream) {
    const float* x   = (const float*)d_in[0];
    const int*   ei  = (const int*)d_in[1];   // [2][E] int32: row0=src, row1=dst
    const float* Wl1 = (const float*)d_in[2];
    const float* Wr1 = (const float*)d_in[3];
    const float* b1  = (const float*)d_in[4];
    const float* Wl2 = (const float*)d_in[5];
    const float* Wr2 = (const float*)d_in[6];
    const float* b2  = (const float*)d_in[7];
    float* out = (float*)d_out;

    const int N = in_sizes[0] / N_FEAT;       // 50000
    const int E = in_sizes[1] / 2;            // 800000
    const int* src = ei;
    const int* dst = ei + E;

    // Workspace carve (bf16 arrays first; all 16-B aligned sizes)
    unsigned short* xb   = (unsigned short*)d_ws;            // N*128 bf16
    unsigned short* aggb = xb + (size_t)N * N_FEAT;          // N*128 bf16 (reused as agg2)
    unsigned short* hb   = aggb + (size_t)N * N_FEAT;        // N*128 bf16
    unsigned short* w1l  = hb + (size_t)N * N_HID;           // 8*4*64*8 = 16384
    unsigned short* w1r  = w1l + 16384;
    unsigned short* w2l  = w1r + 16384;                      // 3*4*64*8 = 6144
    unsigned short* w2r  = w2l + 6144;
    int* cnt = (int*)(w2r + 6144 + 8 /*align pad*/);
    cnt = (int*)(((uintptr_t)cnt + 15) & ~(uintptr_t)15);
    int* off = cnt + N;
    int* cur = off + N + 1;
    int* srt = cur + N;

    hipMemsetAsync(cnt, 0, (size_t)N * sizeof(int), stream);

    const int TB = 256;
    int eblocks = (E + TB - 1) / TB;

    // Conversions / weight swizzles (independent of CSR)
    k_cvt<<<((N * N_FEAT / 4) + TB - 1) / TB, TB, 0, stream>>>(x, xb, N * N_FEAT);
    k_swz<<<(8 * 4 * 64 + TB - 1) / TB, TB, 0, stream>>>(Wl1, w1l, N_HID, 8);
    k_swz<<<(8 * 4 * 64 + TB - 1) / TB, TB, 0, stream>>>(Wr1, w1r, N_HID, 8);
    k_swz<<<(3 * 4 * 64 + TB - 1) / TB, TB, 0, stream>>>(Wl2, w2l, N_CLASS, 3);
    k_swz<<<(3 * 4 * 64 + TB - 1) / TB, TB, 0, stream>>>(Wr2, w2r, N_CLASS, 3);

    // CSR build
    k_count<<<eblocks, TB, 0, stream>>>(dst, cnt, E);
    k_scan<<<1, 1024, 0, stream>>>(cnt, off, cur, N);
    k_fill<<<eblocks, TB, 0, stream>>>(src, dst, cur, srt, E);

    int aggblocks = (N * 64 + TB - 1) / TB;   // one wave per node
    int gblocks = ((N + 15) / 16 + 3) / 4;    // 16 nodes/wave, 4 waves/block

    // Layer 1
    k_aggb<<<aggblocks, TB, 0, stream>>>(xb, srt, off, cnt, aggb, N);
    k_gemm1m<<<gblocks, TB, 0, stream>>>(aggb, xb, w1l, w1r, b1, hb, N);

    // Layer 2
    k_aggb<<<aggblocks, TB, 0, stream>>>(hb, srt, off, cnt, aggb, N);
    k_gemm2m<<<gblocks, TB, 0, stream>>>(aggb, hb, w2l, w2r, b2, out, N);
}

// Round 6
// 320.604 us; speedup vs baseline: 2.5602x; 1.1372x over previous
//
#include <hip/hip_runtime.h>
#include <hip/hip_bf16.h>

#define N_FEAT 128
#define N_HID  128
#define N_CLASS 40

typedef __attribute__((ext_vector_type(8))) __bf16 bf16x8;
typedef __attribute__((ext_vector_type(4))) float f32x4;

__device__ __forceinline__ unsigned short f2bf(float f) {
    union { float f; unsigned int u; } v; v.f = f;
    unsigned int r = (v.u + 0x7FFFu + ((v.u >> 16) & 1u)) >> 16;
    return (unsigned short)r;
}
__device__ __forceinline__ float bf2f_lo(unsigned int p) {
    union { unsigned int u; float f; } v; v.u = p << 16; return v.f;
}
__device__ __forceinline__ float bf2f_hi(unsigned int p) {
    union { unsigned int u; float f; } v; v.u = p & 0xFFFF0000u; return v.f;
}

// ---------------------------------------------------------------------------
// CSR build: count degrees
// ---------------------------------------------------------------------------
__global__ void k_count(const int* __restrict__ dst, int* __restrict__ cnt, int E) {
    int e = blockIdx.x * blockDim.x + threadIdx.x;
    if (e < E) atomicAdd(&cnt[dst[e]], 1);
}

// ---------------------------------------------------------------------------
// Hierarchical scan (R5: single-block k_scan was 53 us at 0.16% occupancy).
// scan1: per-block (256 elems) sums.  scan2: 1-block scan of block sums
// (nb<=256).  scan3: block-local exclusive scan + block offset -> off, cur.
// ---------------------------------------------------------------------------
__global__ __launch_bounds__(256) void k_scan1(const int* __restrict__ cnt,
                                               int* __restrict__ bsum, int n) {
    int i = blockIdx.x * 256 + threadIdx.x;
    int v = (i < n) ? cnt[i] : 0;
    #pragma unroll
    for (int s = 1; s < 64; s <<= 1) v += __shfl_xor(v, s);
    __shared__ int ws[4];
    if ((threadIdx.x & 63) == 0) ws[threadIdx.x >> 6] = v;
    __syncthreads();
    if (threadIdx.x == 0) bsum[blockIdx.x] = ws[0] + ws[1] + ws[2] + ws[3];
}

__global__ __launch_bounds__(256) void k_scan2(const int* __restrict__ bsum,
                                               int* __restrict__ bexc,
                                               int nb, int* __restrict__ off, int n) {
    int tid = threadIdx.x;
    int lane = tid & 63, wid = tid >> 6;
    int v = (tid < nb) ? bsum[tid] : 0;
    int inc = v;
    #pragma unroll
    for (int s = 1; s < 64; s <<= 1) {
        int t = __shfl_up(inc, s);
        if (lane >= s) inc += t;
    }
    __shared__ int ws[4];
    if (lane == 63) ws[wid] = inc;
    __syncthreads();
    int wbase = 0;
    for (int w = 0; w < wid; ++w) wbase += ws[w];
    int exc = wbase + inc - v;
    if (tid < nb) bexc[tid] = exc;
    if (tid == nb - 1) off[n] = exc + v;   // total == E
}

__global__ __launch_bounds__(256) void k_scan3(const int* __restrict__ cnt,
                                               const int* __restrict__ bexc,
                                               int* __restrict__ off,
                                               int* __restrict__ cur, int n) {
    int i = blockIdx.x * 256 + threadIdx.x;
    int lane = threadIdx.x & 63, wid = threadIdx.x >> 6;
    int v = (i < n) ? cnt[i] : 0;
    int inc = v;
    #pragma unroll
    for (int s = 1; s < 64; s <<= 1) {
        int t = __shfl_up(inc, s);
        if (lane >= s) inc += t;
    }
    __shared__ int ws[4];
    if (lane == 63) ws[wid] = inc;
    __syncthreads();
    int wbase = 0;
    for (int w = 0; w < wid; ++w) wbase += ws[w];
    int exc = bexc[blockIdx.x] + wbase + inc - v;
    if (i < n) { off[i] = exc; cur[i] = exc; }
}

// ---------------------------------------------------------------------------
// CSR build: scatter src ids into per-dst buckets
// ---------------------------------------------------------------------------
__global__ void k_fill(const int* __restrict__ src, const int* __restrict__ dst,
                       int* __restrict__ cur, int* __restrict__ srt, int E) {
    int e = blockIdx.x * blockDim.x + threadIdx.x;
    if (e < E) {
        int p = atomicAdd(&cur[dst[e]], 1);
        srt[p] = src[e];
    }
}

// ---------------------------------------------------------------------------
// fp32 -> bf16 bulk convert (n multiple of 4)
// ---------------------------------------------------------------------------
__global__ void k_cvt(const float* __restrict__ in, unsigned short* __restrict__ outp, int n) {
    int i = (blockIdx.x * 256 + threadIdx.x) * 4;
    if (i >= n) return;
    float4 v = *(const float4*)(in + i);
    ushort4 o;
    o.x = f2bf(v.x); o.y = f2bf(v.y); o.z = f2bf(v.z); o.w = f2bf(v.w);
    *(ushort4*)(outp + i) = o;
}

// ---------------------------------------------------------------------------
// Weight swizzle into MFMA B-fragment order (bf16).
// ---------------------------------------------------------------------------
__global__ void k_swz(const float* __restrict__ W, unsigned short* __restrict__ sw,
                      int ncols, int nt) {
    int t = blockIdx.x * 256 + threadIdx.x;
    if (t >= nt * 4 * 64) return;
    int lane = t & 63;
    int bi = t >> 6;
    int kc = bi & 3, ct = bi >> 2;
    int n = lane & 15, q = lane >> 4;
    int col = ct * 16 + n;
    #pragma unroll
    for (int j = 0; j < 8; ++j) {
        int k = kc * 32 + q * 8 + j;
        float f = (col < ncols) ? W[(size_t)k * ncols + col] : 0.f;
        sw[(size_t)t * 8 + j] = f2bf(f);
    }
}

// ---------------------------------------------------------------------------
// Mean aggregation over bf16 features, 2 edges per iteration:
// wave = 1 node; half 0 (lanes 0-31) sums even edges, half 1 odd edges;
// lane covers cols 4*(lane&31)..+3 via one 8-B load. Halves combined with
// __shfl_xor(32); lanes 0-31 store 8 B each (256 B coalesced row).
// Degree from off[n+1]-off[n] (no cnt array read).
// ---------------------------------------------------------------------------
__global__ __launch_bounds__(256) void k_aggb(const unsigned short* __restrict__ feat,
                                              const int* __restrict__ srt,
                                              const int* __restrict__ off,
                                              unsigned short* __restrict__ outp, int n_nodes) {
    int wave = (blockIdx.x * blockDim.x + threadIdx.x) >> 6;
    int lane = threadIdx.x & 63;
    if (wave >= n_nodes) return;
    int beg = off[wave];
    int end = off[wave + 1];
    int half = lane >> 5;
    int cl = lane & 31;            // cols 4*cl .. 4*cl+3
    float ax = 0.f, ay = 0.f, az = 0.f, aw = 0.f;
    for (int e = beg + half; e < end; e += 2) {
        int s = srt[e];
        uint2 p = *(const uint2*)(feat + (size_t)s * N_FEAT + cl * 4);
        ax += bf2f_lo(p.x);
        ay += bf2f_hi(p.x);
        az += bf2f_lo(p.y);
        aw += bf2f_hi(p.y);
    }
    ax += __shfl_xor(ax, 32);
    ay += __shfl_xor(ay, 32);
    az += __shfl_xor(az, 32);
    aw += __shfl_xor(aw, 32);
    if (half == 0) {
        int c = end - beg;
        float inv = 1.0f / (float)(c > 1 ? c : 1);
        uint2 o;
        o.x = ((unsigned int)f2bf(ay * inv) << 16) | f2bf(ax * inv);
        o.y = ((unsigned int)f2bf(aw * inv) << 16) | f2bf(az * inv);
        *(uint2*)(outp + (size_t)wave * N_FEAT + cl * 4) = o;
    }
}

// ---------------------------------------------------------------------------
// GEMM1 via MFMA 16x16x32 bf16: h = relu(agg@Wl + x@Wr + b), bf16 out.
// ---------------------------------------------------------------------------
__global__ __launch_bounds__(256) void k_gemm1m(const unsigned short* __restrict__ aggb,
                                                const unsigned short* __restrict__ xb,
                                                const unsigned short* __restrict__ Bl,
                                                const unsigned short* __restrict__ Br,
                                                const float* __restrict__ bias,
                                                unsigned short* __restrict__ hb, int n_nodes) {
    int wid = (blockIdx.x * 256 + threadIdx.x) >> 6;
    int lane = threadIdx.x & 63;
    int nb = wid * 16;
    if (nb >= n_nodes) return;                 // wave-uniform
    int m = lane & 15, q = lane >> 4;
    size_t abase = (size_t)(nb + m) * N_FEAT + q * 8;
    bf16x8 Aa0 = *(const bf16x8*)(aggb + abase);
    bf16x8 Aa1 = *(const bf16x8*)(aggb + abase + 32);
    bf16x8 Aa2 = *(const bf16x8*)(aggb + abase + 64);
    bf16x8 Aa3 = *(const bf16x8*)(aggb + abase + 96);
    bf16x8 Ax0 = *(const bf16x8*)(xb + abase);
    bf16x8 Ax1 = *(const bf16x8*)(xb + abase + 32);
    bf16x8 Ax2 = *(const bf16x8*)(xb + abase + 64);
    bf16x8 Ax3 = *(const bf16x8*)(xb + abase + 96);
    const bf16x8* blp = (const bf16x8*)Bl + lane;
    const bf16x8* brp = (const bf16x8*)Br + lane;

    #pragma unroll
    for (int ct = 0; ct < 8; ++ct) {
        f32x4 acc = {0.f, 0.f, 0.f, 0.f};
        acc = __builtin_amdgcn_mfma_f32_16x16x32_bf16(Aa0, blp[(ct*4+0)*64], acc, 0,0,0);
        acc = __builtin_amdgcn_mfma_f32_16x16x32_bf16(Ax0, brp[(ct*4+0)*64], acc, 0,0,0);
        acc = __builtin_amdgcn_mfma_f32_16x16x32_bf16(Aa1, blp[(ct*4+1)*64], acc, 0,0,0);
        acc = __builtin_amdgcn_mfma_f32_16x16x32_bf16(Ax1, brp[(ct*4+1)*64], acc, 0,0,0);
        acc = __builtin_amdgcn_mfma_f32_16x16x32_bf16(Aa2, blp[(ct*4+2)*64], acc, 0,0,0);
        acc = __builtin_amdgcn_mfma_f32_16x16x32_bf16(Ax2, brp[(ct*4+2)*64], acc, 0,0,0);
        acc = __builtin_amdgcn_mfma_f32_16x16x32_bf16(Aa3, blp[(ct*4+3)*64], acc, 0,0,0);
        acc = __builtin_amdgcn_mfma_f32_16x16x32_bf16(Ax3, brp[(ct*4+3)*64], acc, 0,0,0);
        int col = ct * 16 + m;
        float bv = bias[col];
        hb[(size_t)(nb + q*4 + 0) * N_HID + col] = f2bf(fmaxf(acc.x + bv, 0.f));
        hb[(size_t)(nb + q*4 + 1) * N_HID + col] = f2bf(fmaxf(acc.y + bv, 0.f));
        hb[(size_t)(nb + q*4 + 2) * N_HID + col] = f2bf(fmaxf(acc.z + bv, 0.f));
        hb[(size_t)(nb + q*4 + 3) * N_HID + col] = f2bf(fmaxf(acc.w + bv, 0.f));
    }
}

// ---------------------------------------------------------------------------
// GEMM2 via MFMA: out = agg2@Wl2 + h@Wr2 + b2, fp32 out, 40 cols.
// ---------------------------------------------------------------------------
__global__ __launch_bounds__(256) void k_gemm2m(const unsigned short* __restrict__ aggb,
                                                const unsigned short* __restrict__ hb,
                                                const unsigned short* __restrict__ Bl,
                                                const unsigned short* __restrict__ Br,
                                                const float* __restrict__ bias,
                                                float* __restrict__ outp, int n_nodes) {
    int wid = (blockIdx.x * 256 + threadIdx.x) >> 6;
    int lane = threadIdx.x & 63;
    int nb = wid * 16;
    if (nb >= n_nodes) return;                 // wave-uniform
    int m = lane & 15, q = lane >> 4;
    size_t abase = (size_t)(nb + m) * N_HID + q * 8;
    bf16x8 Aa0 = *(const bf16x8*)(aggb + abase);
    bf16x8 Aa1 = *(const bf16x8*)(aggb + abase + 32);
    bf16x8 Aa2 = *(const bf16x8*)(aggb + abase + 64);
    bf16x8 Aa3 = *(const bf16x8*)(aggb + abase + 96);
    bf16x8 Ah0 = *(const bf16x8*)(hb + abase);
    bf16x8 Ah1 = *(const bf16x8*)(hb + abase + 32);
    bf16x8 Ah2 = *(const bf16x8*)(hb + abase + 64);
    bf16x8 Ah3 = *(const bf16x8*)(hb + abase + 96);
    const bf16x8* blp = (const bf16x8*)Bl + lane;
    const bf16x8* brp = (const bf16x8*)Br + lane;

    #pragma unroll
    for (int ct = 0; ct < 3; ++ct) {
        f32x4 acc = {0.f, 0.f, 0.f, 0.f};
        acc = __builtin_amdgcn_mfma_f32_16x16x32_bf16(Aa0, blp[(ct*4+0)*64], acc, 0,0,0);
        acc = __builtin_amdgcn_mfma_f32_16x16x32_bf16(Ah0, brp[(ct*4+0)*64], acc, 0,0,0);
        acc = __builtin_amdgcn_mfma_f32_16x16x32_bf16(Aa1, blp[(ct*4+1)*64], acc, 0,0,0);
        acc = __builtin_amdgcn_mfma_f32_16x16x32_bf16(Ah1, brp[(ct*4+1)*64], acc, 0,0,0);
        acc = __builtin_amdgcn_mfma_f32_16x16x32_bf16(Aa2, blp[(ct*4+2)*64], acc, 0,0,0);
        acc = __builtin_amdgcn_mfma_f32_16x16x32_bf16(Ah2, brp[(ct*4+2)*64], acc, 0,0,0);
        acc = __builtin_amdgcn_mfma_f32_16x16x32_bf16(Aa3, blp[(ct*4+3)*64], acc, 0,0,0);
        acc = __builtin_amdgcn_mfma_f32_16x16x32_bf16(Ah3, brp[(ct*4+3)*64], acc, 0,0,0);
        int col = ct * 16 + m;
        if (col < N_CLASS) {
            float bv = bias[col];
            outp[(size_t)(nb + q*4 + 0) * N_CLASS + col] = acc.x + bv;
            outp[(size_t)(nb + q*4 + 1) * N_CLASS + col] = acc.y + bv;
            outp[(size_t)(nb + q*4 + 2) * N_CLASS + col] = acc.z + bv;
            outp[(size_t)(nb + q*4 + 3) * N_CLASS + col] = acc.w + bv;
        }
    }
}

extern "C" void kernel_launch(void* const* d_in, const int* in_sizes, int n_in,
                              void* d_out, int out_size, void* d_ws, size_t ws_size,
                              hipStream_t stream) {
    const float* x   = (const float*)d_in[0];
    const int*   ei  = (const int*)d_in[1];   // [2][E] int32: row0=src, row1=dst
    const float* Wl1 = (const float*)d_in[2];
    const float* Wr1 = (const float*)d_in[3];
    const float* b1  = (const float*)d_in[4];
    const float* Wl2 = (const float*)d_in[5];
    const float* Wr2 = (const float*)d_in[6];
    const float* b2  = (const float*)d_in[7];
    float* out = (float*)d_out;

    const int N = in_sizes[0] / N_FEAT;       // 50000
    const int E = in_sizes[1] / 2;            // 800000
    const int* src = ei;
    const int* dst = ei + E;

    // Workspace carve
    unsigned short* xb   = (unsigned short*)d_ws;            // N*128 bf16
    unsigned short* aggb = xb + (size_t)N * N_FEAT;          // N*128 bf16 (reused)
    unsigned short* hb   = aggb + (size_t)N * N_FEAT;        // N*128 bf16
    unsigned short* w1l  = hb + (size_t)N * N_HID;           // 16384
    unsigned short* w1r  = w1l + 16384;
    unsigned short* w2l  = w1r + 16384;                      // 6144
    unsigned short* w2r  = w2l + 6144;
    int* cnt = (int*)(w2r + 6144 + 8);
    cnt = (int*)(((uintptr_t)cnt + 15) & ~(uintptr_t)15);
    int* off = cnt + N;                                      // N+1
    int* cur = off + N + 1;                                  // N
    int* srt = cur + N;                                      // E
    int* bsum = srt + E;                                     // nblocks
    int* bexc = bsum + 256;                                  // nblocks

    hipMemsetAsync(cnt, 0, (size_t)N * sizeof(int), stream);

    const int TB = 256;
    int eblocks = (E + TB - 1) / TB;
    int sblocks = (N + TB - 1) / TB;          // 196 <= 256 (k_scan2 limit)

    // Conversions / weight swizzles (independent of CSR)
    k_cvt<<<((N * N_FEAT / 4) + TB - 1) / TB, TB, 0, stream>>>(x, xb, N * N_FEAT);
    k_swz<<<(8 * 4 * 64 + TB - 1) / TB, TB, 0, stream>>>(Wl1, w1l, N_HID, 8);
    k_swz<<<(8 * 4 * 64 + TB - 1) / TB, TB, 0, stream>>>(Wr1, w1r, N_HID, 8);
    k_swz<<<(3 * 4 * 64 + TB - 1) / TB, TB, 0, stream>>>(Wl2, w2l, N_CLASS, 3);
    k_swz<<<(3 * 4 * 64 + TB - 1) / TB, TB, 0, stream>>>(Wr2, w2r, N_CLASS, 3);

    // CSR build
    k_count<<<eblocks, TB, 0, stream>>>(dst, cnt, E);
    k_scan1<<<sblocks, TB, 0, stream>>>(cnt, bsum, N);
    k_scan2<<<1, TB, 0, stream>>>(bsum, bexc, sblocks, off, N);
    k_scan3<<<sblocks, TB, 0, stream>>>(cnt, bexc, off, cur, N);
    k_fill<<<eblocks, TB, 0, stream>>>(src, dst, cur, srt, E);

    int aggblocks = (N * 64 + TB - 1) / TB;   // one wave per node
    int gblocks = ((N + 15) / 16 + 3) / 4;    // 16 nodes/wave, 4 waves/block

    // Layer 1
    k_aggb<<<aggblocks, TB, 0, stream>>>(xb, srt, off, aggb, N);
    k_gemm1m<<<gblocks, TB, 0, stream>>>(aggb, xb, w1l, w1r, b1, hb, N);

    // Layer 2
    k_aggb<<<aggblocks, TB, 0, stream>>>(hb, srt, off, aggb, N);
    k_gemm2m<<<gblocks, TB, 0, stream>>>(aggb, hb, w2l, w2r, b2, out, N);
}

// Round 7
// 269.921 us; speedup vs baseline: 3.0410x; 1.1878x over previous
//
#include <hip/hip_runtime.h>
#include <hip/hip_bf16.h>

#define N_FEAT 128
#define N_HID  128
#define N_CLASS 40

typedef __attribute__((ext_vector_type(8))) __bf16 bf16x8;
typedef __attribute__((ext_vector_type(4))) float f32x4;

__device__ __forceinline__ unsigned short f2bf(float f) {
    union { float f; unsigned int u; } v; v.f = f;
    unsigned int r = (v.u + 0x7FFFu + ((v.u >> 16) & 1u)) >> 16;
    return (unsigned short)r;
}
__device__ __forceinline__ float bf2f_lo(unsigned int p) {
    union { unsigned int u; float f; } v; v.u = p << 16; return v.f;
}
__device__ __forceinline__ float bf2f_hi(unsigned int p) {
    union { unsigned int u; float f; } v; v.u = p & 0xFFFF0000u; return v.f;
}

// ---------------------------------------------------------------------------
// CSR build: count degrees
// ---------------------------------------------------------------------------
__global__ void k_count(const int* __restrict__ dst, int* __restrict__ cnt, int E) {
    int e = blockIdx.x * blockDim.x + threadIdx.x;
    if (e < E) atomicAdd(&cnt[dst[e]], 1);
}

// ---------------------------------------------------------------------------
// Hierarchical scan: per-block sums -> 1-block scan of sums -> local scan.
// ---------------------------------------------------------------------------
__global__ __launch_bounds__(256) void k_scan1(const int* __restrict__ cnt,
                                               int* __restrict__ bsum, int n) {
    int i = blockIdx.x * 256 + threadIdx.x;
    int v = (i < n) ? cnt[i] : 0;
    #pragma unroll
    for (int s = 1; s < 64; s <<= 1) v += __shfl_xor(v, s);
    __shared__ int ws[4];
    if ((threadIdx.x & 63) == 0) ws[threadIdx.x >> 6] = v;
    __syncthreads();
    if (threadIdx.x == 0) bsum[blockIdx.x] = ws[0] + ws[1] + ws[2] + ws[3];
}

__global__ __launch_bounds__(256) void k_scan2(const int* __restrict__ bsum,
                                               int* __restrict__ bexc,
                                               int nb, int* __restrict__ off, int n) {
    int tid = threadIdx.x;
    int lane = tid & 63, wid = tid >> 6;
    int v = (tid < nb) ? bsum[tid] : 0;
    int inc = v;
    #pragma unroll
    for (int s = 1; s < 64; s <<= 1) {
        int t = __shfl_up(inc, s);
        if (lane >= s) inc += t;
    }
    __shared__ int ws[4];
    if (lane == 63) ws[wid] = inc;
    __syncthreads();
    int wbase = 0;
    for (int w = 0; w < wid; ++w) wbase += ws[w];
    int exc = wbase + inc - v;
    if (tid < nb) bexc[tid] = exc;
    if (tid == nb - 1) off[n] = exc + v;   // total == E
}

__global__ __launch_bounds__(256) void k_scan3(const int* __restrict__ cnt,
                                               const int* __restrict__ bexc,
                                               int* __restrict__ off,
                                               int* __restrict__ cur, int n) {
    int i = blockIdx.x * 256 + threadIdx.x;
    int lane = threadIdx.x & 63, wid = threadIdx.x >> 6;
    int v = (i < n) ? cnt[i] : 0;
    int inc = v;
    #pragma unroll
    for (int s = 1; s < 64; s <<= 1) {
        int t = __shfl_up(inc, s);
        if (lane >= s) inc += t;
    }
    __shared__ int ws[4];
    if (lane == 63) ws[wid] = inc;
    __syncthreads();
    int wbase = 0;
    for (int w = 0; w < wid; ++w) wbase += ws[w];
    int exc = bexc[blockIdx.x] + wbase + inc - v;
    if (i < n) { off[i] = exc; cur[i] = exc; }
}

// ---------------------------------------------------------------------------
// CSR build: scatter src ids into per-dst buckets
// ---------------------------------------------------------------------------
__global__ void k_fill(const int* __restrict__ src, const int* __restrict__ dst,
                       int* __restrict__ cur, int* __restrict__ srt, int E) {
    int e = blockIdx.x * blockDim.x + threadIdx.x;
    if (e < E) {
        int p = atomicAdd(&cur[dst[e]], 1);
        srt[p] = src[e];
    }
}

// ---------------------------------------------------------------------------
// fp32 -> bf16 bulk convert
// ---------------------------------------------------------------------------
__global__ void k_cvt(const float* __restrict__ in, unsigned short* __restrict__ outp, int n) {
    int i = (blockIdx.x * 256 + threadIdx.x) * 4;
    if (i >= n) return;
    float4 v = *(const float4*)(in + i);
    ushort4 o;
    o.x = f2bf(v.x); o.y = f2bf(v.y); o.z = f2bf(v.z); o.w = f2bf(v.w);
    *(ushort4*)(outp + i) = o;
}

// ---------------------------------------------------------------------------
// Weight swizzle into MFMA B-fragment order (bf16), layer-1 weights.
// ---------------------------------------------------------------------------
__global__ void k_swz(const float* __restrict__ W, unsigned short* __restrict__ sw,
                      int ncols, int nt) {
    int t = blockIdx.x * 256 + threadIdx.x;
    if (t >= nt * 4 * 64) return;
    int lane = t & 63;
    int bi = t >> 6;
    int kc = bi & 3, ct = bi >> 2;
    int n = lane & 15, q = lane >> 4;
    int col = ct * 16 + n;
    #pragma unroll
    for (int j = 0; j < 8; ++j) {
        int k = kc * 32 + q * 8 + j;
        float f = (col < ncols) ? W[(size_t)k * ncols + col] : 0.f;
        sw[(size_t)t * 8 + j] = f2bf(f);
    }
}

// ---------------------------------------------------------------------------
// Combined layer-2 weight swizzle: logical W = [Wl2 | Wr2] (128 x 80), 5 tiles.
// ---------------------------------------------------------------------------
__global__ void k_swzc(const float* __restrict__ Wl2, const float* __restrict__ Wr2,
                       unsigned short* __restrict__ sw) {
    int t = blockIdx.x * 256 + threadIdx.x;
    if (t >= 5 * 4 * 64) return;
    int lane = t & 63;
    int bi = t >> 6;
    int kc = bi & 3, ct = bi >> 2;
    int n = lane & 15, q = lane >> 4;
    int col = ct * 16 + n;          // 0..79
    #pragma unroll
    for (int j = 0; j < 8; ++j) {
        int k = kc * 32 + q * 8 + j;
        float f = (col < N_CLASS) ? Wl2[(size_t)k * N_CLASS + col]
                                  : Wr2[(size_t)k * N_CLASS + (col - N_CLASS)];
        sw[(size_t)t * 8 + j] = f2bf(f);
    }
}

// ---------------------------------------------------------------------------
// Mean aggregation, 128 bf16 cols: quarter-wave (16 lanes x 16 B) per edge,
// 4 edges concurrent + 2-deep pipeline (8 gathers in flight per wave).
// Combine quarters via shfl_xor(16,32); lanes 0-15 store 16 B each.
// ---------------------------------------------------------------------------
__global__ __launch_bounds__(256) void k_aggb4(const unsigned short* __restrict__ feat,
                                               const int* __restrict__ srt,
                                               const int* __restrict__ off,
                                               unsigned short* __restrict__ outp, int n_nodes) {
    int wave = (blockIdx.x * blockDim.x + threadIdx.x) >> 6;
    int lane = threadIdx.x & 63;
    if (wave >= n_nodes) return;
    int q = lane >> 4;             // edge slot 0..3
    int l = lane & 15;             // cols 8l..8l+7 (16 B)
    int beg = off[wave];
    int end = off[wave + 1];
    float a0 = 0.f, a1 = 0.f, a2 = 0.f, a3 = 0.f,
          a4 = 0.f, a5 = 0.f, a6 = 0.f, a7 = 0.f;
    int e = beg + q;
    #define ACCUM128(P) { \
        a0 += bf2f_lo(P.x); a1 += bf2f_hi(P.x); \
        a2 += bf2f_lo(P.y); a3 += bf2f_hi(P.y); \
        a4 += bf2f_lo(P.z); a5 += bf2f_hi(P.z); \
        a6 += bf2f_lo(P.w); a7 += bf2f_hi(P.w); }
    for (; e + 4 < end; e += 8) {
        int s0 = srt[e];
        int s1 = srt[e + 4];
        uint4 p0 = *(const uint4*)(feat + (size_t)s0 * N_FEAT + l * 8);
        uint4 p1 = *(const uint4*)(feat + (size_t)s1 * N_FEAT + l * 8);
        ACCUM128(p0)
        ACCUM128(p1)
    }
    if (e < end) {
        int s0 = srt[e];
        uint4 p0 = *(const uint4*)(feat + (size_t)s0 * N_FEAT + l * 8);
        ACCUM128(p0)
    }
    #undef ACCUM128
    #define RED(A) A += __shfl_xor(A, 16); A += __shfl_xor(A, 32);
    RED(a0) RED(a1) RED(a2) RED(a3) RED(a4) RED(a5) RED(a6) RED(a7)
    #undef RED
    if (q == 0) {
        int c = end - beg;
        float inv = 1.0f / (float)(c > 1 ? c : 1);
        uint4 o;
        o.x = ((unsigned int)f2bf(a1 * inv) << 16) | f2bf(a0 * inv);
        o.y = ((unsigned int)f2bf(a3 * inv) << 16) | f2bf(a2 * inv);
        o.z = ((unsigned int)f2bf(a5 * inv) << 16) | f2bf(a4 * inv);
        o.w = ((unsigned int)f2bf(a7 * inv) << 16) | f2bf(a6 * inv);
        *(uint4*)(outp + (size_t)wave * N_FEAT + l * 8) = o;
    }
}

// ---------------------------------------------------------------------------
// Layer-2 tail: out[n,c] = mean_{s in nbr(n)} P2[s,c] + R2[n,c], c<40.
// P2 rows padded to 64 bf16 (128 B); quarter-wave (16 lanes x 8 B) per edge.
// ---------------------------------------------------------------------------
__global__ __launch_bounds__(256) void k_agg40(const unsigned short* __restrict__ p2b,
                                               const float* __restrict__ r2,
                                               const int* __restrict__ srt,
                                               const int* __restrict__ off,
                                               float* __restrict__ outp, int n_nodes) {
    int wave = (blockIdx.x * blockDim.x + threadIdx.x) >> 6;
    int lane = threadIdx.x & 63;
    if (wave >= n_nodes) return;
    int q = lane >> 4;             // edge slot
    int l = lane & 15;             // cols 4l..4l+3 (8 B)
    int beg = off[wave];
    int end = off[wave + 1];
    float a0 = 0.f, a1 = 0.f, a2 = 0.f, a3 = 0.f;
    int e = beg + q;
    #define ACCUM64(P) { \
        a0 += bf2f_lo(P.x); a1 += bf2f_hi(P.x); \
        a2 += bf2f_lo(P.y); a3 += bf2f_hi(P.y); }
    for (; e + 4 < end; e += 8) {
        int s0 = srt[e];
        int s1 = srt[e + 4];
        uint2 p0 = *(const uint2*)(p2b + (size_t)s0 * 64 + l * 4);
        uint2 p1 = *(const uint2*)(p2b + (size_t)s1 * 64 + l * 4);
        ACCUM64(p0)
        ACCUM64(p1)
    }
    if (e < end) {
        int s0 = srt[e];
        uint2 p0 = *(const uint2*)(p2b + (size_t)s0 * 64 + l * 4);
        ACCUM64(p0)
    }
    #undef ACCUM64
    #define RED(A) A += __shfl_xor(A, 16); A += __shfl_xor(A, 32);
    RED(a0) RED(a1) RED(a2) RED(a3)
    #undef RED
    if (lane < 10) {               // q==0, cols 4*lane..+3 < 40
        int c = end - beg;
        float inv = 1.0f / (float)(c > 1 ? c : 1);
        float4 rr = *(const float4*)(r2 + (size_t)wave * N_CLASS + lane * 4);
        float4 o;
        o.x = fmaf(a0, inv, rr.x);
        o.y = fmaf(a1, inv, rr.y);
        o.z = fmaf(a2, inv, rr.z);
        o.w = fmaf(a3, inv, rr.w);
        *(float4*)(outp + (size_t)wave * N_CLASS + lane * 4) = o;
    }
}

// ---------------------------------------------------------------------------
// GEMM1 via MFMA 16x16x32 bf16: h = relu(agg@Wl + x@Wr + b), bf16 out.
// ---------------------------------------------------------------------------
__global__ __launch_bounds__(256) void k_gemm1m(const unsigned short* __restrict__ aggb,
                                                const unsigned short* __restrict__ xb,
                                                const unsigned short* __restrict__ Bl,
                                                const unsigned short* __restrict__ Br,
                                                const float* __restrict__ bias,
                                                unsigned short* __restrict__ hb, int n_nodes) {
    int wid = (blockIdx.x * 256 + threadIdx.x) >> 6;
    int lane = threadIdx.x & 63;
    int nb = wid * 16;
    if (nb >= n_nodes) return;                 // wave-uniform
    int m = lane & 15, q = lane >> 4;
    size_t abase = (size_t)(nb + m) * N_FEAT + q * 8;
    bf16x8 Aa0 = *(const bf16x8*)(aggb + abase);
    bf16x8 Aa1 = *(const bf16x8*)(aggb + abase + 32);
    bf16x8 Aa2 = *(const bf16x8*)(aggb + abase + 64);
    bf16x8 Aa3 = *(const bf16x8*)(aggb + abase + 96);
    bf16x8 Ax0 = *(const bf16x8*)(xb + abase);
    bf16x8 Ax1 = *(const bf16x8*)(xb + abase + 32);
    bf16x8 Ax2 = *(const bf16x8*)(xb + abase + 64);
    bf16x8 Ax3 = *(const bf16x8*)(xb + abase + 96);
    const bf16x8* blp = (const bf16x8*)Bl + lane;
    const bf16x8* brp = (const bf16x8*)Br + lane;

    #pragma unroll
    for (int ct = 0; ct < 8; ++ct) {
        f32x4 acc = {0.f, 0.f, 0.f, 0.f};
        acc = __builtin_amdgcn_mfma_f32_16x16x32_bf16(Aa0, blp[(ct*4+0)*64], acc, 0,0,0);
        acc = __builtin_amdgcn_mfma_f32_16x16x32_bf16(Ax0, brp[(ct*4+0)*64], acc, 0,0,0);
        acc = __builtin_amdgcn_mfma_f32_16x16x32_bf16(Aa1, blp[(ct*4+1)*64], acc, 0,0,0);
        acc = __builtin_amdgcn_mfma_f32_16x16x32_bf16(Ax1, brp[(ct*4+1)*64], acc, 0,0,0);
        acc = __builtin_amdgcn_mfma_f32_16x16x32_bf16(Aa2, blp[(ct*4+2)*64], acc, 0,0,0);
        acc = __builtin_amdgcn_mfma_f32_16x16x32_bf16(Ax2, brp[(ct*4+2)*64], acc, 0,0,0);
        acc = __builtin_amdgcn_mfma_f32_16x16x32_bf16(Aa3, blp[(ct*4+3)*64], acc, 0,0,0);
        acc = __builtin_amdgcn_mfma_f32_16x16x32_bf16(Ax3, brp[(ct*4+3)*64], acc, 0,0,0);
        int col = ct * 16 + m;
        float bv = bias[col];
        hb[(size_t)(nb + q*4 + 0) * N_HID + col] = f2bf(fmaxf(acc.x + bv, 0.f));
        hb[(size_t)(nb + q*4 + 1) * N_HID + col] = f2bf(fmaxf(acc.y + bv, 0.f));
        hb[(size_t)(nb + q*4 + 2) * N_HID + col] = f2bf(fmaxf(acc.z + bv, 0.f));
        hb[(size_t)(nb + q*4 + 3) * N_HID + col] = f2bf(fmaxf(acc.w + bv, 0.f));
    }
}

// ---------------------------------------------------------------------------
// GEMM2 projection: [P2|R2] = h @ [Wl2|Wr2]  (128 -> 80 cols, 5 tiles).
// P2 (cols 0-39) -> bf16, rows padded to 64; R2 (cols 40-79) -> fp32 + b2.
// ---------------------------------------------------------------------------
__global__ __launch_bounds__(256) void k_gemm2p(const unsigned short* __restrict__ hb,
                                                const unsigned short* __restrict__ Bc,
                                                const float* __restrict__ bias2,
                                                unsigned short* __restrict__ p2b,
                                                float* __restrict__ r2, int n_nodes) {
    int wid = (blockIdx.x * 256 + threadIdx.x) >> 6;
    int lane = threadIdx.x & 63;
    int nb = wid * 16;
    if (nb >= n_nodes) return;                 // wave-uniform
    int m = lane & 15, q = lane >> 4;
    size_t abase = (size_t)(nb + m) * N_HID + q * 8;
    bf16x8 Ah0 = *(const bf16x8*)(hb + abase);
    bf16x8 Ah1 = *(const bf16x8*)(hb + abase + 32);
    bf16x8 Ah2 = *(const bf16x8*)(hb + abase + 64);
    bf16x8 Ah3 = *(const bf16x8*)(hb + abase + 96);
    const bf16x8* bcp = (const bf16x8*)Bc + lane;

    #pragma unroll
    for (int ct = 0; ct < 5; ++ct) {
        f32x4 acc = {0.f, 0.f, 0.f, 0.f};
        acc = __builtin_amdgcn_mfma_f32_16x16x32_bf16(Ah0, bcp[(ct*4+0)*64], acc, 0,0,0);
        acc = __builtin_amdgcn_mfma_f32_16x16x32_bf16(Ah1, bcp[(ct*4+1)*64], acc, 0,0,0);
        acc = __builtin_amdgcn_mfma_f32_16x16x32_bf16(Ah2, bcp[(ct*4+2)*64], acc, 0,0,0);
        acc = __builtin_amdgcn_mfma_f32_16x16x32_bf16(Ah3, bcp[(ct*4+3)*64], acc, 0,0,0);
        int col = ct * 16 + m;
        if (col < N_CLASS) {
            p2b[(size_t)(nb + q*4 + 0) * 64 + col] = f2bf(acc.x);
            p2b[(size_t)(nb + q*4 + 1) * 64 + col] = f2bf(acc.y);
            p2b[(size_t)(nb + q*4 + 2) * 64 + col] = f2bf(acc.z);
            p2b[(size_t)(nb + q*4 + 3) * 64 + col] = f2bf(acc.w);
        } else {
            int rc = col - N_CLASS;
            float bv = bias2[rc];
            r2[(size_t)(nb + q*4 + 0) * N_CLASS + rc] = acc.x + bv;
            r2[(size_t)(nb + q*4 + 1) * N_CLASS + rc] = acc.y + bv;
            r2[(size_t)(nb + q*4 + 2) * N_CLASS + rc] = acc.z + bv;
            r2[(size_t)(nb + q*4 + 3) * N_CLASS + rc] = acc.w + bv;
        }
    }
}

extern "C" void kernel_launch(void* const* d_in, const int* in_sizes, int n_in,
                              void* d_out, int out_size, void* d_ws, size_t ws_size,
                              hipStream_t stream) {
    const float* x   = (const float*)d_in[0];
    const int*   ei  = (const int*)d_in[1];   // [2][E] int32: row0=src, row1=dst
    const float* Wl1 = (const float*)d_in[2];
    const float* Wr1 = (const float*)d_in[3];
    const float* b1  = (const float*)d_in[4];
    const float* Wl2 = (const float*)d_in[5];
    const float* Wr2 = (const float*)d_in[6];
    const float* b2  = (const float*)d_in[7];
    float* out = (float*)d_out;

    const int N = in_sizes[0] / N_FEAT;       // 50000
    const int E = in_sizes[1] / 2;            // 800000
    const int* src = ei;
    const int* dst = ei + E;

    // Workspace carve (16-B aligned pieces)
    unsigned short* xb   = (unsigned short*)d_ws;            // N*128 bf16
    unsigned short* aggb = xb + (size_t)N * N_FEAT;          // N*128 bf16
    unsigned short* hb   = aggb + (size_t)N * N_FEAT;        // N*128 bf16
    unsigned short* p2b  = hb + (size_t)N * N_HID;           // N*64 bf16 (P2 padded)
    float* r2 = (float*)(p2b + (size_t)N * 64);              // N*40 fp32
    unsigned short* w1l  = (unsigned short*)(r2 + (size_t)N * N_CLASS);  // 16384
    unsigned short* w1r  = w1l + 16384;
    unsigned short* wc   = w1r + 16384;                      // 5*4*64*8 = 10240
    int* cnt = (int*)(wc + 10240);
    cnt = (int*)(((uintptr_t)cnt + 15) & ~(uintptr_t)15);
    int* off = cnt + N;                                      // N+1
    int* cur = off + N + 1;                                  // N
    int* srt = cur + N;                                      // E
    int* bsum = srt + E;                                     // <=256
    int* bexc = bsum + 256;                                  // <=256

    hipMemsetAsync(cnt, 0, (size_t)N * sizeof(int), stream);

    const int TB = 256;
    int eblocks = (E + TB - 1) / TB;
    int sblocks = (N + TB - 1) / TB;          // 196 <= 256 (k_scan2 limit)

    // Conversions / weight swizzles (independent of CSR)
    k_cvt<<<((N * N_FEAT / 4) + TB - 1) / TB, TB, 0, stream>>>(x, xb, N * N_FEAT);
    k_swz<<<(8 * 4 * 64 + TB - 1) / TB, TB, 0, stream>>>(Wl1, w1l, N_HID, 8);
    k_swz<<<(8 * 4 * 64 + TB - 1) / TB, TB, 0, stream>>>(Wr1, w1r, N_HID, 8);
    k_swzc<<<(5 * 4 * 64 + TB - 1) / TB, TB, 0, stream>>>(Wl2, Wr2, wc);

    // CSR build
    k_count<<<eblocks, TB, 0, stream>>>(dst, cnt, E);
    k_scan1<<<sblocks, TB, 0, stream>>>(cnt, bsum, N);
    k_scan2<<<1, TB, 0, stream>>>(bsum, bexc, sblocks, off, N);
    k_scan3<<<sblocks, TB, 0, stream>>>(cnt, bexc, off, cur, N);
    k_fill<<<eblocks, TB, 0, stream>>>(src, dst, cur, srt, E);

    int aggblocks = (N * 64 + TB - 1) / TB;   // one wave per node
    int gblocks = ((N + 15) / 16 + 3) / 4;    // 16 nodes/wave, 4 waves/block

    // Layer 1
    k_aggb4<<<aggblocks, TB, 0, stream>>>(xb, srt, off, aggb, N);
    k_gemm1m<<<gblocks, TB, 0, stream>>>(aggb, xb, w1l, w1r, b1, hb, N);

    // Layer 2: project first (mean is linear), then aggregate 40 cols + add R2
    k_gemm2p<<<gblocks, TB, 0, stream>>>(hb, wc, b2, p2b, r2, N);
    k_agg40<<<aggblocks, TB, 0, stream>>>(p2b, r2, srt, off, out, N);
}

// Round 8
// 222.008 us; speedup vs baseline: 3.6973x; 1.2158x over previous
//
#include <hip/hip_runtime.h>
#include <hip/hip_bf16.h>

#define N_FEAT 128
#define N_HID  128
#define N_CLASS 40

// Binned CSR-build constants: 256 partitions of 196 nodes (256*196=50176>=50000)
#define NP   256
#define PSZ  196
#define BCAP 4096   // pairs per partition bin; mean 3125, +17 sigma headroom
#define BCHUNK 4096 // edges per k_bin block

typedef __attribute__((ext_vector_type(8))) __bf16 bf16x8;
typedef __attribute__((ext_vector_type(4))) float f32x4;

__device__ __forceinline__ unsigned short f2bf(float f) {
    union { float f; unsigned int u; } v; v.f = f;
    unsigned int r = (v.u + 0x7FFFu + ((v.u >> 16) & 1u)) >> 16;
    return (unsigned short)r;
}
__device__ __forceinline__ float bf2f_lo(unsigned int p) {
    union { unsigned int u; float f; } v; v.u = p << 16; return v.f;
}
__device__ __forceinline__ float bf2f_hi(unsigned int p) {
    union { unsigned int u; float f; } v; v.u = p & 0xFFFF0000u; return v.f;
}

// ---------------------------------------------------------------------------
// Pass 1: bin edges into 256 dst-partition pair lists, coalesced writes.
// (R7: k_fill's random 4-B scatter caused 52 MB write-back for 3.2 MB payload.)
// ---------------------------------------------------------------------------
__global__ __launch_bounds__(256) void k_bin(const int* __restrict__ src,
                                             const int* __restrict__ dst,
                                             int* __restrict__ ptail,
                                             uint2* __restrict__ bins, int E) {
    __shared__ uint2 stage[BCHUNK];
    __shared__ int lcnt[NP], lofs[NP], lcur[NP], gbase[NP];
    __shared__ int ws4[4];
    int t = threadIdx.x;
    int base = blockIdx.x * BCHUNK;
    int nE = min(BCHUNK, E - base);
    lcnt[t] = 0;
    __syncthreads();
    for (int i = t; i < nE; i += 256) {
        int d = dst[base + i];
        atomicAdd(&lcnt[d / PSZ], 1);
    }
    __syncthreads();
    {   // block-wide exclusive scan of lcnt -> lofs; reserve global space
        int v = lcnt[t];
        int lane = t & 63, wid = t >> 6;
        int inc = v;
        #pragma unroll
        for (int s = 1; s < 64; s <<= 1) {
            int u = __shfl_up(inc, s);
            if (lane >= s) inc += u;
        }
        if (lane == 63) ws4[wid] = inc;
        __syncthreads();
        int wb = 0;
        for (int w = 0; w < wid; ++w) wb += ws4[w];
        int exc = wb + inc - v;
        lofs[t] = exc;
        lcur[t] = exc;
        gbase[t] = atomicAdd(&ptail[t], v);
    }
    __syncthreads();
    for (int i = t; i < nE; i += 256) {
        int d = dst[base + i];
        int s = src[base + i];
        int pos = atomicAdd(&lcur[d / PSZ], 1);
        stage[pos] = make_uint2((unsigned)s, (unsigned)d);
    }
    __syncthreads();
    for (int i = t; i < nE; i += 256) {   // partition-contiguous -> coalesced
        uint2 pr = stage[i];
        int p = (int)pr.y / PSZ;
        bins[(size_t)p * BCAP + gbase[p] + (i - lofs[p])] = pr;
    }
}

// ---------------------------------------------------------------------------
// Pass 2a: per-partition degree histogram in LDS -> cnt (coalesced write).
// Replaces k_count + cnt memset.
// ---------------------------------------------------------------------------
__global__ __launch_bounds__(256) void k_pcount(const uint2* __restrict__ bins,
                                                const int* __restrict__ ptail,
                                                int* __restrict__ cnt, int N) {
    int p = blockIdx.x;
    __shared__ int lc[PSZ];
    int t = threadIdx.x;
    if (t < PSZ) lc[t] = 0;
    __syncthreads();
    int n = ptail[p];
    const uint2* bp = bins + (size_t)p * BCAP;
    for (int i = t; i < n; i += 256)
        atomicAdd(&lc[(int)bp[i].y - p * PSZ], 1);
    __syncthreads();
    int g = p * PSZ + t;
    if (t < PSZ && g < N) cnt[g] = lc[t];
}

// ---------------------------------------------------------------------------
// Pass 2b: per-partition placement. Scatter target is one block's 12.5 KB
// region -> L2-local, lines written back once.
// ---------------------------------------------------------------------------
__global__ __launch_bounds__(256) void k_place(const uint2* __restrict__ bins,
                                               const int* __restrict__ ptail,
                                               const int* __restrict__ off,
                                               int* __restrict__ srt, int N) {
    int p = blockIdx.x;
    __shared__ int lcur[PSZ];
    int t = threadIdx.x;
    int g = p * PSZ + t;
    if (t < PSZ) lcur[t] = (g < N) ? off[g] : 0;
    __syncthreads();
    int n = ptail[p];
    const uint2* bp = bins + (size_t)p * BCAP;
    for (int i = t; i < n; i += 256) {
        uint2 pr = bp[i];
        int pos = atomicAdd(&lcur[(int)pr.y - p * PSZ], 1);
        srt[pos] = (int)pr.x;
    }
}

// ---------------------------------------------------------------------------
// Hierarchical scan: per-block sums -> 1-block scan of sums -> local scan.
// ---------------------------------------------------------------------------
__global__ __launch_bounds__(256) void k_scan1(const int* __restrict__ cnt,
                                               int* __restrict__ bsum, int n) {
    int i = blockIdx.x * 256 + threadIdx.x;
    int v = (i < n) ? cnt[i] : 0;
    #pragma unroll
    for (int s = 1; s < 64; s <<= 1) v += __shfl_xor(v, s);
    __shared__ int ws[4];
    if ((threadIdx.x & 63) == 0) ws[threadIdx.x >> 6] = v;
    __syncthreads();
    if (threadIdx.x == 0) bsum[blockIdx.x] = ws[0] + ws[1] + ws[2] + ws[3];
}

__global__ __launch_bounds__(256) void k_scan2(const int* __restrict__ bsum,
                                               int* __restrict__ bexc,
                                               int nb, int* __restrict__ off, int n) {
    int tid = threadIdx.x;
    int lane = tid & 63, wid = tid >> 6;
    int v = (tid < nb) ? bsum[tid] : 0;
    int inc = v;
    #pragma unroll
    for (int s = 1; s < 64; s <<= 1) {
        int t = __shfl_up(inc, s);
        if (lane >= s) inc += t;
    }
    __shared__ int ws[4];
    if (lane == 63) ws[wid] = inc;
    __syncthreads();
    int wbase = 0;
    for (int w = 0; w < wid; ++w) wbase += ws[w];
    int exc = wbase + inc - v;
    if (tid < nb) bexc[tid] = exc;
    if (tid == nb - 1) off[n] = exc + v;   // total == E
}

__global__ __launch_bounds__(256) void k_scan3(const int* __restrict__ cnt,
                                               const int* __restrict__ bexc,
                                               int* __restrict__ off, int n) {
    int i = blockIdx.x * 256 + threadIdx.x;
    int lane = threadIdx.x & 63, wid = threadIdx.x >> 6;
    int v = (i < n) ? cnt[i] : 0;
    int inc = v;
    #pragma unroll
    for (int s = 1; s < 64; s <<= 1) {
        int t = __shfl_up(inc, s);
        if (lane >= s) inc += t;
    }
    __shared__ int ws[4];
    if (lane == 63) ws[wid] = inc;
    __syncthreads();
    int wbase = 0;
    for (int w = 0; w < wid; ++w) wbase += ws[w];
    int exc = bexc[blockIdx.x] + wbase + inc - v;
    if (i < n) off[i] = exc;
}

// ---------------------------------------------------------------------------
// fp32 -> bf16 bulk convert
// ---------------------------------------------------------------------------
__global__ void k_cvt(const float* __restrict__ in, unsigned short* __restrict__ outp, int n) {
    int i = (blockIdx.x * 256 + threadIdx.x) * 4;
    if (i >= n) return;
    float4 v = *(const float4*)(in + i);
    ushort4 o;
    o.x = f2bf(v.x); o.y = f2bf(v.y); o.z = f2bf(v.z); o.w = f2bf(v.w);
    *(ushort4*)(outp + i) = o;
}

// ---------------------------------------------------------------------------
// Weight swizzle into MFMA B-fragment order (bf16), layer-1 weights.
// ---------------------------------------------------------------------------
__global__ void k_swz(const float* __restrict__ W, unsigned short* __restrict__ sw,
                      int ncols, int nt) {
    int t = blockIdx.x * 256 + threadIdx.x;
    if (t >= nt * 4 * 64) return;
    int lane = t & 63;
    int bi = t >> 6;
    int kc = bi & 3, ct = bi >> 2;
    int n = lane & 15, q = lane >> 4;
    int col = ct * 16 + n;
    #pragma unroll
    for (int j = 0; j < 8; ++j) {
        int k = kc * 32 + q * 8 + j;
        float f = (col < ncols) ? W[(size_t)k * ncols + col] : 0.f;
        sw[(size_t)t * 8 + j] = f2bf(f);
    }
}

// ---------------------------------------------------------------------------
// Combined layer-2 weight swizzle: logical W = [Wl2 | Wr2] (128 x 80), 5 tiles.
// ---------------------------------------------------------------------------
__global__ void k_swzc(const float* __restrict__ Wl2, const float* __restrict__ Wr2,
                       unsigned short* __restrict__ sw) {
    int t = blockIdx.x * 256 + threadIdx.x;
    if (t >= 5 * 4 * 64) return;
    int lane = t & 63;
    int bi = t >> 6;
    int kc = bi & 3, ct = bi >> 2;
    int n = lane & 15, q = lane >> 4;
    int col = ct * 16 + n;          // 0..79
    #pragma unroll
    for (int j = 0; j < 8; ++j) {
        int k = kc * 32 + q * 8 + j;
        float f = (col < N_CLASS) ? Wl2[(size_t)k * N_CLASS + col]
                                  : Wr2[(size_t)k * N_CLASS + (col - N_CLASS)];
        sw[(size_t)t * 8 + j] = f2bf(f);
    }
}

// ---------------------------------------------------------------------------
// Mean aggregation, 128 bf16 cols: quarter-wave (16 lanes x 16 B) per edge,
// 4 edges concurrent + 2-deep pipeline; combine via shfl_xor(16,32).
// ---------------------------------------------------------------------------
__global__ __launch_bounds__(256) void k_aggb4(const unsigned short* __restrict__ feat,
                                               const int* __restrict__ srt,
                                               const int* __restrict__ off,
                                               unsigned short* __restrict__ outp, int n_nodes) {
    int wave = (blockIdx.x * blockDim.x + threadIdx.x) >> 6;
    int lane = threadIdx.x & 63;
    if (wave >= n_nodes) return;
    int q = lane >> 4;             // edge slot 0..3
    int l = lane & 15;             // cols 8l..8l+7 (16 B)
    int beg = off[wave];
    int end = off[wave + 1];
    float a0 = 0.f, a1 = 0.f, a2 = 0.f, a3 = 0.f,
          a4 = 0.f, a5 = 0.f, a6 = 0.f, a7 = 0.f;
    int e = beg + q;
    #define ACCUM128(P) { \
        a0 += bf2f_lo(P.x); a1 += bf2f_hi(P.x); \
        a2 += bf2f_lo(P.y); a3 += bf2f_hi(P.y); \
        a4 += bf2f_lo(P.z); a5 += bf2f_hi(P.z); \
        a6 += bf2f_lo(P.w); a7 += bf2f_hi(P.w); }
    for (; e + 4 < end; e += 8) {
        int s0 = srt[e];
        int s1 = srt[e + 4];
        uint4 p0 = *(const uint4*)(feat + (size_t)s0 * N_FEAT + l * 8);
        uint4 p1 = *(const uint4*)(feat + (size_t)s1 * N_FEAT + l * 8);
        ACCUM128(p0)
        ACCUM128(p1)
    }
    if (e < end) {
        int s0 = srt[e];
        uint4 p0 = *(const uint4*)(feat + (size_t)s0 * N_FEAT + l * 8);
        ACCUM128(p0)
    }
    #undef ACCUM128
    #define RED(A) A += __shfl_xor(A, 16); A += __shfl_xor(A, 32);
    RED(a0) RED(a1) RED(a2) RED(a3) RED(a4) RED(a5) RED(a6) RED(a7)
    #undef RED
    if (q == 0) {
        int c = end - beg;
        float inv = 1.0f / (float)(c > 1 ? c : 1);
        uint4 o;
        o.x = ((unsigned int)f2bf(a1 * inv) << 16) | f2bf(a0 * inv);
        o.y = ((unsigned int)f2bf(a3 * inv) << 16) | f2bf(a2 * inv);
        o.z = ((unsigned int)f2bf(a5 * inv) << 16) | f2bf(a4 * inv);
        o.w = ((unsigned int)f2bf(a7 * inv) << 16) | f2bf(a6 * inv);
        *(uint4*)(outp + (size_t)wave * N_FEAT + l * 8) = o;
    }
}

// ---------------------------------------------------------------------------
// Layer-2 tail: out[n,c] = mean_{s in nbr(n)} P2[s,c] + R2[n,c], c<40.
// ---------------------------------------------------------------------------
__global__ __launch_bounds__(256) void k_agg40(const unsigned short* __restrict__ p2b,
                                               const float* __restrict__ r2,
                                               const int* __restrict__ srt,
                                               const int* __restrict__ off,
                                               float* __restrict__ outp, int n_nodes) {
    int wave = (blockIdx.x * blockDim.x + threadIdx.x) >> 6;
    int lane = threadIdx.x & 63;
    if (wave >= n_nodes) return;
    int q = lane >> 4;             // edge slot
    int l = lane & 15;             // cols 4l..4l+3 (8 B)
    int beg = off[wave];
    int end = off[wave + 1];
    float a0 = 0.f, a1 = 0.f, a2 = 0.f, a3 = 0.f;
    int e = beg + q;
    #define ACCUM64(P) { \
        a0 += bf2f_lo(P.x); a1 += bf2f_hi(P.x); \
        a2 += bf2f_lo(P.y); a3 += bf2f_hi(P.y); }
    for (; e + 4 < end; e += 8) {
        int s0 = srt[e];
        int s1 = srt[e + 4];
        uint2 p0 = *(const uint2*)(p2b + (size_t)s0 * 64 + l * 4);
        uint2 p1 = *(const uint2*)(p2b + (size_t)s1 * 64 + l * 4);
        ACCUM64(p0)
        ACCUM64(p1)
    }
    if (e < end) {
        int s0 = srt[e];
        uint2 p0 = *(const uint2*)(p2b + (size_t)s0 * 64 + l * 4);
        ACCUM64(p0)
    }
    #undef ACCUM64
    #define RED(A) A += __shfl_xor(A, 16); A += __shfl_xor(A, 32);
    RED(a0) RED(a1) RED(a2) RED(a3)
    #undef RED
    if (lane < 10) {               // q==0, cols 4*lane..+3 < 40
        int c = end - beg;
        float inv = 1.0f / (float)(c > 1 ? c : 1);
        float4 rr = *(const float4*)(r2 + (size_t)wave * N_CLASS + lane * 4);
        float4 o;
        o.x = fmaf(a0, inv, rr.x);
        o.y = fmaf(a1, inv, rr.y);
        o.z = fmaf(a2, inv, rr.z);
        o.w = fmaf(a3, inv, rr.w);
        *(float4*)(outp + (size_t)wave * N_CLASS + lane * 4) = o;
    }
}

// ---------------------------------------------------------------------------
// GEMM1 via MFMA 16x16x32 bf16: h = relu(agg@Wl + x@Wr + b), bf16 out.
// ---------------------------------------------------------------------------
__global__ __launch_bounds__(256) void k_gemm1m(const unsigned short* __restrict__ aggb,
                                                const unsigned short* __restrict__ xb,
                                                const unsigned short* __restrict__ Bl,
                                                const unsigned short* __restrict__ Br,
                                                const float* __restrict__ bias,
                                                unsigned short* __restrict__ hb, int n_nodes) {
    int wid = (blockIdx.x * 256 + threadIdx.x) >> 6;
    int lane = threadIdx.x & 63;
    int nb = wid * 16;
    if (nb >= n_nodes) return;                 // wave-uniform
    int m = lane & 15, q = lane >> 4;
    size_t abase = (size_t)(nb + m) * N_FEAT + q * 8;
    bf16x8 Aa0 = *(const bf16x8*)(aggb + abase);
    bf16x8 Aa1 = *(const bf16x8*)(aggb + abase + 32);
    bf16x8 Aa2 = *(const bf16x8*)(aggb + abase + 64);
    bf16x8 Aa3 = *(const bf16x8*)(aggb + abase + 96);
    bf16x8 Ax0 = *(const bf16x8*)(xb + abase);
    bf16x8 Ax1 = *(const bf16x8*)(xb + abase + 32);
    bf16x8 Ax2 = *(const bf16x8*)(xb + abase + 64);
    bf16x8 Ax3 = *(const bf16x8*)(xb + abase + 96);
    const bf16x8* blp = (const bf16x8*)Bl + lane;
    const bf16x8* brp = (const bf16x8*)Br + lane;

    #pragma unroll
    for (int ct = 0; ct < 8; ++ct) {
        f32x4 acc = {0.f, 0.f, 0.f, 0.f};
        acc = __builtin_amdgcn_mfma_f32_16x16x32_bf16(Aa0, blp[(ct*4+0)*64], acc, 0,0,0);
        acc = __builtin_amdgcn_mfma_f32_16x16x32_bf16(Ax0, brp[(ct*4+0)*64], acc, 0,0,0);
        acc = __builtin_amdgcn_mfma_f32_16x16x32_bf16(Aa1, blp[(ct*4+1)*64], acc, 0,0,0);
        acc = __builtin_amdgcn_mfma_f32_16x16x32_bf16(Ax1, brp[(ct*4+1)*64], acc, 0,0,0);
        acc = __builtin_amdgcn_mfma_f32_16x16x32_bf16(Aa2, blp[(ct*4+2)*64], acc, 0,0,0);
        acc = __builtin_amdgcn_mfma_f32_16x16x32_bf16(Ax2, brp[(ct*4+2)*64], acc, 0,0,0);
        acc = __builtin_amdgcn_mfma_f32_16x16x32_bf16(Aa3, blp[(ct*4+3)*64], acc, 0,0,0);
        acc = __builtin_amdgcn_mfma_f32_16x16x32_bf16(Ax3, brp[(ct*4+3)*64], acc, 0,0,0);
        int col = ct * 16 + m;
        float bv = bias[col];
        hb[(size_t)(nb + q*4 + 0) * N_HID + col] = f2bf(fmaxf(acc.x + bv, 0.f));
        hb[(size_t)(nb + q*4 + 1) * N_HID + col] = f2bf(fmaxf(acc.y + bv, 0.f));
        hb[(size_t)(nb + q*4 + 2) * N_HID + col] = f2bf(fmaxf(acc.z + bv, 0.f));
        hb[(size_t)(nb + q*4 + 3) * N_HID + col] = f2bf(fmaxf(acc.w + bv, 0.f));
    }
}

// ---------------------------------------------------------------------------
// GEMM2 projection: [P2|R2] = h @ [Wl2|Wr2]  (128 -> 80 cols, 5 tiles).
// ---------------------------------------------------------------------------
__global__ __launch_bounds__(256) void k_gemm2p(const unsigned short* __restrict__ hb,
                                                const unsigned short* __restrict__ Bc,
                                                const float* __restrict__ bias2,
                                                unsigned short* __restrict__ p2b,
                                                float* __restrict__ r2, int n_nodes) {
    int wid = (blockIdx.x * 256 + threadIdx.x) >> 6;
    int lane = threadIdx.x & 63;
    int nb = wid * 16;
    if (nb >= n_nodes) return;                 // wave-uniform
    int m = lane & 15, q = lane >> 4;
    size_t abase = (size_t)(nb + m) * N_HID + q * 8;
    bf16x8 Ah0 = *(const bf16x8*)(hb + abase);
    bf16x8 Ah1 = *(const bf16x8*)(hb + abase + 32);
    bf16x8 Ah2 = *(const bf16x8*)(hb + abase + 64);
    bf16x8 Ah3 = *(const bf16x8*)(hb + abase + 96);
    const bf16x8* bcp = (const bf16x8*)Bc + lane;

    #pragma unroll
    for (int ct = 0; ct < 5; ++ct) {
        f32x4 acc = {0.f, 0.f, 0.f, 0.f};
        acc = __builtin_amdgcn_mfma_f32_16x16x32_bf16(Ah0, bcp[(ct*4+0)*64], acc, 0,0,0);
        acc = __builtin_amdgcn_mfma_f32_16x16x32_bf16(Ah1, bcp[(ct*4+1)*64], acc, 0,0,0);
        acc = __builtin_amdgcn_mfma_f32_16x16x32_bf16(Ah2, bcp[(ct*4+2)*64], acc, 0,0,0);
        acc = __builtin_amdgcn_mfma_f32_16x16x32_bf16(Ah3, bcp[(ct*4+3)*64], acc, 0,0,0);
        int col = ct * 16 + m;
        if (col < N_CLASS) {
            p2b[(size_t)(nb + q*4 + 0) * 64 + col] = f2bf(acc.x);
            p2b[(size_t)(nb + q*4 + 1) * 64 + col] = f2bf(acc.y);
            p2b[(size_t)(nb + q*4 + 2) * 64 + col] = f2bf(acc.z);
            p2b[(size_t)(nb + q*4 + 3) * 64 + col] = f2bf(acc.w);
        } else {
            int rc = col - N_CLASS;
            float bv = bias2[rc];
            r2[(size_t)(nb + q*4 + 0) * N_CLASS + rc] = acc.x + bv;
            r2[(size_t)(nb + q*4 + 1) * N_CLASS + rc] = acc.y + bv;
            r2[(size_t)(nb + q*4 + 2) * N_CLASS + rc] = acc.z + bv;
            r2[(size_t)(nb + q*4 + 3) * N_CLASS + rc] = acc.w + bv;
        }
    }
}

extern "C" void kernel_launch(void* const* d_in, const int* in_sizes, int n_in,
                              void* d_out, int out_size, void* d_ws, size_t ws_size,
                              hipStream_t stream) {
    const float* x   = (const float*)d_in[0];
    const int*   ei  = (const int*)d_in[1];   // [2][E] int32: row0=src, row1=dst
    const float* Wl1 = (const float*)d_in[2];
    const float* Wr1 = (const float*)d_in[3];
    const float* b1  = (const float*)d_in[4];
    const float* Wl2 = (const float*)d_in[5];
    const float* Wr2 = (const float*)d_in[6];
    const float* b2  = (const float*)d_in[7];
    float* out = (float*)d_out;

    const int N = in_sizes[0] / N_FEAT;       // 50000
    const int E = in_sizes[1] / 2;            // 800000
    const int* src = ei;
    const int* dst = ei + E;

    // Workspace carve. bins (8.4 MB) aliases the p2b/r2 region (14.4 MB):
    // bins is dead after k_place, p2b/r2 are written only in k_gemm2p (later).
    unsigned short* xb   = (unsigned short*)d_ws;            // N*128 bf16
    unsigned short* aggb = xb + (size_t)N * N_FEAT;          // N*128 bf16
    unsigned short* hb   = aggb + (size_t)N * N_FEAT;        // N*128 bf16
    unsigned short* p2b  = hb + (size_t)N * N_HID;           // N*64 bf16
    float* r2 = (float*)(p2b + (size_t)N * 64);              // N*40 fp32
    uint2* bins = (uint2*)p2b;                               // NP*BCAP uint2 (alias)
    unsigned short* w1l  = (unsigned short*)(r2 + (size_t)N * N_CLASS);  // 16384
    unsigned short* w1r  = w1l + 16384;
    unsigned short* wc   = w1r + 16384;                      // 10240
    int* cnt = (int*)(wc + 10240);
    cnt = (int*)(((uintptr_t)cnt + 15) & ~(uintptr_t)15);
    int* off = cnt + N;                                      // N+1
    int* srt = off + N + 1;                                  // E
    int* ptail = srt + E;                                    // NP
    int* bsum = ptail + NP;                                  // <=256
    int* bexc = bsum + 256;                                  // <=256

    hipMemsetAsync(ptail, 0, NP * sizeof(int), stream);

    const int TB = 256;
    int sblocks = (N + TB - 1) / TB;          // 196 <= 256 (k_scan2 limit)
    int bblocks = (E + BCHUNK - 1) / BCHUNK;  // 196

    // Conversions / weight swizzles (independent of CSR)
    k_cvt<<<((N * N_FEAT / 4) + TB - 1) / TB, TB, 0, stream>>>(x, xb, N * N_FEAT);
    k_swz<<<(8 * 4 * 64 + TB - 1) / TB, TB, 0, stream>>>(Wl1, w1l, N_HID, 8);
    k_swz<<<(8 * 4 * 64 + TB - 1) / TB, TB, 0, stream>>>(Wr1, w1r, N_HID, 8);
    k_swzc<<<(5 * 4 * 64 + TB - 1) / TB, TB, 0, stream>>>(Wl2, Wr2, wc);

    // Binned CSR build
    k_bin<<<bblocks, TB, 0, stream>>>(src, dst, ptail, bins, E);
    k_pcount<<<NP, TB, 0, stream>>>(bins, ptail, cnt, N);
    k_scan1<<<sblocks, TB, 0, stream>>>(cnt, bsum, N);
    k_scan2<<<1, TB, 0, stream>>>(bsum, bexc, sblocks, off, N);
    k_scan3<<<sblocks, TB, 0, stream>>>(cnt, bexc, off, N);
    k_place<<<NP, TB, 0, stream>>>(bins, ptail, off, srt, N);

    int aggblocks = (N * 64 + TB - 1) / TB;   // one wave per node
    int gblocks = ((N + 15) / 16 + 3) / 4;    // 16 nodes/wave, 4 waves/block

    // Layer 1
    k_aggb4<<<aggblocks, TB, 0, stream>>>(xb, srt, off, aggb, N);
    k_gemm1m<<<gblocks, TB, 0, stream>>>(aggb, xb, w1l, w1r, b1, hb, N);

    // Layer 2: project first (mean is linear), then aggregate 40 cols + add R2
    k_gemm2p<<<gblocks, TB, 0, stream>>>(hb, wc, b2, p2b, r2, N);
    k_agg40<<<aggblocks, TB, 0, stream>>>(p2b, r2, srt, off, out, N);
}

// Round 9
// 189.483 us; speedup vs baseline: 4.3319x; 1.1717x over previous
//
#include <hip/hip_runtime.h>
#include <hip/hip_bf16.h>

#define N_FEAT 128
#define N_HID  128
#define N_CLASS 40

// Binned CSR-build constants: 256 partitions of 196 nodes (256*196=50176>=50000)
#define NP   256
#define PSZ  196
#define BCAP 4096   // pairs per partition bin; mean 3125, +17 sigma headroom
#define BCHUNK 4096 // edges per k_bin block

#define HSTRIDE 136 // LDS row stride (bf16) for h tile: 272 B, 16-B aligned

typedef __attribute__((ext_vector_type(8))) __bf16 bf16x8;
typedef __attribute__((ext_vector_type(4))) float f32x4;

__device__ __forceinline__ unsigned short f2bf(float f) {
    union { float f; unsigned int u; } v; v.f = f;
    unsigned int r = (v.u + 0x7FFFu + ((v.u >> 16) & 1u)) >> 16;
    return (unsigned short)r;
}
__device__ __forceinline__ float bf2f_lo(unsigned int p) {
    union { unsigned int u; float f; } v; v.u = p << 16; return v.f;
}
__device__ __forceinline__ float bf2f_hi(unsigned int p) {
    union { unsigned int u; float f; } v; v.u = p & 0xFFFF0000u; return v.f;
}

// ---------------------------------------------------------------------------
// Weight swizzle bodies (MFMA B-fragment order).
// ---------------------------------------------------------------------------
__device__ __forceinline__ void swz_body(const float* __restrict__ W,
                                         unsigned short* __restrict__ sw,
                                         int ncols, int t, int nt) {
    if (t >= nt * 4 * 64) return;
    int lane = t & 63;
    int bi = t >> 6;
    int kc = bi & 3, ct = bi >> 2;
    int n = lane & 15, q = lane >> 4;
    int col = ct * 16 + n;
    #pragma unroll
    for (int j = 0; j < 8; ++j) {
        int k = kc * 32 + q * 8 + j;
        float f = (col < ncols) ? W[(size_t)k * ncols + col] : 0.f;
        sw[(size_t)t * 8 + j] = f2bf(f);
    }
}
__device__ __forceinline__ void swzc_body(const float* __restrict__ Wl2,
                                          const float* __restrict__ Wr2,
                                          unsigned short* __restrict__ sw, int t) {
    if (t >= 5 * 4 * 64) return;
    int lane = t & 63;
    int bi = t >> 6;
    int kc = bi & 3, ct = bi >> 2;
    int n = lane & 15, q = lane >> 4;
    int col = ct * 16 + n;          // 0..79
    #pragma unroll
    for (int j = 0; j < 8; ++j) {
        int k = kc * 32 + q * 8 + j;
        float f = (col < N_CLASS) ? Wl2[(size_t)k * N_CLASS + col]
                                  : Wr2[(size_t)k * N_CLASS + (col - N_CLASS)];
        sw[(size_t)t * 8 + j] = f2bf(f);
    }
}

// ---------------------------------------------------------------------------
// Prep: x->bf16 convert + all weight swizzles + ptail zeroing, one launch.
// ---------------------------------------------------------------------------
__global__ __launch_bounds__(256) void k_prep(const float* __restrict__ x,
                                              unsigned short* __restrict__ xb, int nCvt, int nElem,
                                              const float* __restrict__ Wl1,
                                              const float* __restrict__ Wr1,
                                              const float* __restrict__ Wl2,
                                              const float* __restrict__ Wr2,
                                              unsigned short* __restrict__ w1l,
                                              unsigned short* __restrict__ w1r,
                                              unsigned short* __restrict__ wc,
                                              int* __restrict__ ptail) {
    int b = blockIdx.x, t = threadIdx.x;
    if (b < nCvt) {
        int i = (b * 256 + t) * 4;
        if (i < nElem) {
            float4 v = *(const float4*)(x + i);
            ushort4 o;
            o.x = f2bf(v.x); o.y = f2bf(v.y); o.z = f2bf(v.z); o.w = f2bf(v.w);
            *(ushort4*)(xb + i) = o;
        }
        return;
    }
    b -= nCvt;
    if (b < 8) { swz_body(Wl1, w1l, N_HID, b * 256 + t, 8); return; }
    b -= 8;
    if (b < 8) { swz_body(Wr1, w1r, N_HID, b * 256 + t, 8); return; }
    b -= 8;
    if (b < 5) { swzc_body(Wl2, Wr2, wc, b * 256 + t); return; }
    // last block: zero partition tails
    ptail[t] = 0;
}

// ---------------------------------------------------------------------------
// Pass 1: bin edges into 256 dst-partition pair lists, coalesced writes.
// ---------------------------------------------------------------------------
__global__ __launch_bounds__(256) void k_bin(const int* __restrict__ src,
                                             const int* __restrict__ dst,
                                             int* __restrict__ ptail,
                                             uint2* __restrict__ bins, int E) {
    __shared__ uint2 stage[BCHUNK];
    __shared__ int lcnt[NP], lofs[NP], lcur[NP], gbase[NP];
    __shared__ int ws4[4];
    int t = threadIdx.x;
    int base = blockIdx.x * BCHUNK;
    int nE = min(BCHUNK, E - base);
    lcnt[t] = 0;
    __syncthreads();
    for (int i = t; i < nE; i += 256) {
        int d = dst[base + i];
        atomicAdd(&lcnt[d / PSZ], 1);
    }
    __syncthreads();
    {   // block-wide exclusive scan of lcnt -> lofs; reserve global space
        int v = lcnt[t];
        int lane = t & 63, wid = t >> 6;
        int inc = v;
        #pragma unroll
        for (int s = 1; s < 64; s <<= 1) {
            int u = __shfl_up(inc, s);
            if (lane >= s) inc += u;
        }
        if (lane == 63) ws4[wid] = inc;
        __syncthreads();
        int wb = 0;
        for (int w = 0; w < wid; ++w) wb += ws4[w];
        int exc = wb + inc - v;
        lofs[t] = exc;
        lcur[t] = exc;
        gbase[t] = atomicAdd(&ptail[t], v);
    }
    __syncthreads();
    for (int i = t; i < nE; i += 256) {
        int d = dst[base + i];
        int s = src[base + i];
        int pos = atomicAdd(&lcur[d / PSZ], 1);
        stage[pos] = make_uint2((unsigned)s, (unsigned)d);
    }
    __syncthreads();
    for (int i = t; i < nE; i += 256) {   // partition-contiguous -> coalesced
        uint2 pr = stage[i];
        int p = (int)pr.y / PSZ;
        bins[(size_t)p * BCAP + gbase[p] + (i - lofs[p])] = pr;
    }
}

// ---------------------------------------------------------------------------
// Pass 2: 1-block exclusive scan of partition totals -> pbase; off[N]=E.
// ---------------------------------------------------------------------------
__global__ __launch_bounds__(256) void k_pscan(const int* __restrict__ ptail,
                                               int* __restrict__ pbase,
                                               int* __restrict__ off, int N) {
    int t = threadIdx.x;
    int lane = t & 63, wid = t >> 6;
    int v = ptail[t];
    int inc = v;
    #pragma unroll
    for (int s = 1; s < 64; s <<= 1) {
        int u = __shfl_up(inc, s);
        if (lane >= s) inc += u;
    }
    __shared__ int ws[4];
    if (lane == 63) ws[wid] = inc;
    __syncthreads();
    int wb = 0;
    for (int w = 0; w < wid; ++w) wb += ws[w];
    pbase[t] = wb + inc - v;
    if (t == NP - 1) off[N] = wb + inc;   // == E
}

// ---------------------------------------------------------------------------
// Pass 3: per-partition histogram -> local scan -> off write -> place srt.
// Scatter stays inside one block's 12.5 KB region (lines written back once).
// ---------------------------------------------------------------------------
__global__ __launch_bounds__(256) void k_build(const uint2* __restrict__ bins,
                                               const int* __restrict__ ptail,
                                               const int* __restrict__ pbase,
                                               int* __restrict__ off,
                                               int* __restrict__ srt, int N) {
    int p = blockIdx.x;
    __shared__ int lc[256], lofs[256];
    __shared__ int ws4[4];
    int t = threadIdx.x;
    lc[t] = 0;
    __syncthreads();
    int n = ptail[p];
    const uint2* bp = bins + (size_t)p * BCAP;
    for (int i = t; i < n; i += 256)
        atomicAdd(&lc[(int)bp[i].y - p * PSZ], 1);
    __syncthreads();
    {   // exclusive scan of lc -> global positions in lofs
        int v = lc[t];
        int lane = t & 63, wid = t >> 6;
        int inc = v;
        #pragma unroll
        for (int s = 1; s < 64; s <<= 1) {
            int u = __shfl_up(inc, s);
            if (lane >= s) inc += u;
        }
        if (lane == 63) ws4[wid] = inc;
        __syncthreads();
        int wb = 0;
        for (int w = 0; w < wid; ++w) wb += ws4[w];
        lofs[t] = pbase[p] + wb + inc - v;
    }
    __syncthreads();
    int g = p * PSZ + t;
    if (t < PSZ && g < N) off[g] = lofs[t];
    __syncthreads();
    for (int i = t; i < n; i += 256) {
        uint2 pr = bp[i];
        int pos = atomicAdd(&lofs[(int)pr.y - p * PSZ], 1);
        srt[pos] = (int)pr.x;
    }
}

// ---------------------------------------------------------------------------
// Mean aggregation, 128 bf16 cols: quarter-wave (16 lanes x 16 B) per edge,
// 4 edges concurrent + 2-deep pipeline; combine via shfl_xor(16,32).
// ---------------------------------------------------------------------------
__global__ __launch_bounds__(256) void k_aggb4(const unsigned short* __restrict__ feat,
                                               const int* __restrict__ srt,
                                               const int* __restrict__ off,
                                               unsigned short* __restrict__ outp, int n_nodes) {
    int wave = (blockIdx.x * blockDim.x + threadIdx.x) >> 6;
    int lane = threadIdx.x & 63;
    if (wave >= n_nodes) return;
    int q = lane >> 4;             // edge slot 0..3
    int l = lane & 15;             // cols 8l..8l+7 (16 B)
    int beg = off[wave];
    int end = off[wave + 1];
    float a0 = 0.f, a1 = 0.f, a2 = 0.f, a3 = 0.f,
          a4 = 0.f, a5 = 0.f, a6 = 0.f, a7 = 0.f;
    int e = beg + q;
    #define ACCUM128(P) { \
        a0 += bf2f_lo(P.x); a1 += bf2f_hi(P.x); \
        a2 += bf2f_lo(P.y); a3 += bf2f_hi(P.y); \
        a4 += bf2f_lo(P.z); a5 += bf2f_hi(P.z); \
        a6 += bf2f_lo(P.w); a7 += bf2f_hi(P.w); }
    for (; e + 4 < end; e += 8) {
        int s0 = srt[e];
        int s1 = srt[e + 4];
        uint4 p0 = *(const uint4*)(feat + (size_t)s0 * N_FEAT + l * 8);
        uint4 p1 = *(const uint4*)(feat + (size_t)s1 * N_FEAT + l * 8);
        ACCUM128(p0)
        ACCUM128(p1)
    }
    if (e < end) {
        int s0 = srt[e];
        uint4 p0 = *(const uint4*)(feat + (size_t)s0 * N_FEAT + l * 8);
        ACCUM128(p0)
    }
    #undef ACCUM128
    #define RED(A) A += __shfl_xor(A, 16); A += __shfl_xor(A, 32);
    RED(a0) RED(a1) RED(a2) RED(a3) RED(a4) RED(a5) RED(a6) RED(a7)
    #undef RED
    if (q == 0) {
        int c = end - beg;
        float inv = 1.0f / (float)(c > 1 ? c : 1);
        uint4 o;
        o.x = ((unsigned int)f2bf(a1 * inv) << 16) | f2bf(a0 * inv);
        o.y = ((unsigned int)f2bf(a3 * inv) << 16) | f2bf(a2 * inv);
        o.z = ((unsigned int)f2bf(a5 * inv) << 16) | f2bf(a4 * inv);
        o.w = ((unsigned int)f2bf(a7 * inv) << 16) | f2bf(a6 * inv);
        *(uint4*)(outp + (size_t)wave * N_FEAT + l * 8) = o;
    }
}

// ---------------------------------------------------------------------------
// Fused GEMM1+projection: h = relu(agg@Wl1 + x@Wr1 + b1) lives only in a
// wave-private LDS tile (stride 136 bf16 -> 16-B aligned rows), then
// [P2|R2] = h @ [Wl2|Wr2]. hb global round-trip (25.6 MB) eliminated.
// P2 packed to 40 cols bf16; R2 fp32 + b2.
// ---------------------------------------------------------------------------
__global__ __launch_bounds__(256) void k_gemm12(const unsigned short* __restrict__ aggb,
                                                const unsigned short* __restrict__ xb,
                                                const unsigned short* __restrict__ Bl,
                                                const unsigned short* __restrict__ Br,
                                                const float* __restrict__ bias1,
                                                const unsigned short* __restrict__ Bc,
                                                const float* __restrict__ bias2,
                                                unsigned short* __restrict__ p2b,
                                                float* __restrict__ r2, int n_nodes) {
    __shared__ unsigned short hlds[4][16 * HSTRIDE];
    int tid = threadIdx.x;
    int wv = tid >> 6;
    int wid = (blockIdx.x * 256 + tid) >> 6;
    int lane = tid & 63;
    int nb = wid * 16;
    if (nb >= n_nodes) return;                 // wave-uniform
    int m = lane & 15, q = lane >> 4;
    size_t abase = (size_t)(nb + m) * N_FEAT + q * 8;
    bf16x8 Aa0 = *(const bf16x8*)(aggb + abase);
    bf16x8 Aa1 = *(const bf16x8*)(aggb + abase + 32);
    bf16x8 Aa2 = *(const bf16x8*)(aggb + abase + 64);
    bf16x8 Aa3 = *(const bf16x8*)(aggb + abase + 96);
    bf16x8 Ax0 = *(const bf16x8*)(xb + abase);
    bf16x8 Ax1 = *(const bf16x8*)(xb + abase + 32);
    bf16x8 Ax2 = *(const bf16x8*)(xb + abase + 64);
    bf16x8 Ax3 = *(const bf16x8*)(xb + abase + 96);
    const bf16x8* blp = (const bf16x8*)Bl + lane;
    const bf16x8* brp = (const bf16x8*)Br + lane;
    unsigned short* hl = hlds[wv];

    #pragma unroll
    for (int ct = 0; ct < 8; ++ct) {
        f32x4 acc = {0.f, 0.f, 0.f, 0.f};
        acc = __builtin_amdgcn_mfma_f32_16x16x32_bf16(Aa0, blp[(ct*4+0)*64], acc, 0,0,0);
        acc = __builtin_amdgcn_mfma_f32_16x16x32_bf16(Ax0, brp[(ct*4+0)*64], acc, 0,0,0);
        acc = __builtin_amdgcn_mfma_f32_16x16x32_bf16(Aa1, blp[(ct*4+1)*64], acc, 0,0,0);
        acc = __builtin_amdgcn_mfma_f32_16x16x32_bf16(Ax1, brp[(ct*4+1)*64], acc, 0,0,0);
        acc = __builtin_amdgcn_mfma_f32_16x16x32_bf16(Aa2, blp[(ct*4+2)*64], acc, 0,0,0);
        acc = __builtin_amdgcn_mfma_f32_16x16x32_bf16(Ax2, brp[(ct*4+2)*64], acc, 0,0,0);
        acc = __builtin_amdgcn_mfma_f32_16x16x32_bf16(Aa3, blp[(ct*4+3)*64], acc, 0,0,0);
        acc = __builtin_amdgcn_mfma_f32_16x16x32_bf16(Ax3, brp[(ct*4+3)*64], acc, 0,0,0);
        int col = ct * 16 + m;
        float bv = bias1[col];
        hl[(q*4 + 0) * HSTRIDE + col] = f2bf(fmaxf(acc.x + bv, 0.f));
        hl[(q*4 + 1) * HSTRIDE + col] = f2bf(fmaxf(acc.y + bv, 0.f));
        hl[(q*4 + 2) * HSTRIDE + col] = f2bf(fmaxf(acc.z + bv, 0.f));
        hl[(q*4 + 3) * HSTRIDE + col] = f2bf(fmaxf(acc.w + bv, 0.f));
    }
    // wave-local LDS: compiler inserts lgkmcnt waits; no barrier needed.
    bf16x8 H0 = *(const bf16x8*)(hl + m * HSTRIDE + q * 8);
    bf16x8 H1 = *(const bf16x8*)(hl + m * HSTRIDE + q * 8 + 32);
    bf16x8 H2 = *(const bf16x8*)(hl + m * HSTRIDE + q * 8 + 64);
    bf16x8 H3 = *(const bf16x8*)(hl + m * HSTRIDE + q * 8 + 96);
    const bf16x8* bcp = (const bf16x8*)Bc + lane;

    #pragma unroll
    for (int ct = 0; ct < 5; ++ct) {
        f32x4 acc = {0.f, 0.f, 0.f, 0.f};
        acc = __builtin_amdgcn_mfma_f32_16x16x32_bf16(H0, bcp[(ct*4+0)*64], acc, 0,0,0);
        acc = __builtin_amdgcn_mfma_f32_16x16x32_bf16(H1, bcp[(ct*4+1)*64], acc, 0,0,0);
        acc = __builtin_amdgcn_mfma_f32_16x16x32_bf16(H2, bcp[(ct*4+2)*64], acc, 0,0,0);
        acc = __builtin_amdgcn_mfma_f32_16x16x32_bf16(H3, bcp[(ct*4+3)*64], acc, 0,0,0);
        int col = ct * 16 + m;
        if (col < N_CLASS) {
            p2b[(size_t)(nb + q*4 + 0) * N_CLASS + col] = f2bf(acc.x);
            p2b[(size_t)(nb + q*4 + 1) * N_CLASS + col] = f2bf(acc.y);
            p2b[(size_t)(nb + q*4 + 2) * N_CLASS + col] = f2bf(acc.z);
            p2b[(size_t)(nb + q*4 + 3) * N_CLASS + col] = f2bf(acc.w);
        } else {
            int rc = col - N_CLASS;
            float bv = bias2[rc];
            r2[(size_t)(nb + q*4 + 0) * N_CLASS + rc] = acc.x + bv;
            r2[(size_t)(nb + q*4 + 1) * N_CLASS + rc] = acc.y + bv;
            r2[(size_t)(nb + q*4 + 2) * N_CLASS + rc] = acc.z + bv;
            r2[(size_t)(nb + q*4 + 3) * N_CLASS + rc] = acc.w + bv;
        }
    }
}

// ---------------------------------------------------------------------------
// Layer-2 tail: out[n,c] = mean_{s in nbr(n)} P2[s,c] + R2[n,c], c<40.
// P2 packed 40 cols (80-B rows, 8-B aligned); lanes l<10 per quarter active.
// ---------------------------------------------------------------------------
__global__ __launch_bounds__(256) void k_agg40(const unsigned short* __restrict__ p2b,
                                               const float* __restrict__ r2,
                                               const int* __restrict__ srt,
                                               const int* __restrict__ off,
                                               float* __restrict__ outp, int n_nodes) {
    int wave = (blockIdx.x * blockDim.x + threadIdx.x) >> 6;
    int lane = threadIdx.x & 63;
    if (wave >= n_nodes) return;
    int q = lane >> 4;             // edge slot
    int l = lane & 15;             // cols 4l..4l+3 (8 B), active l<10
    bool act = l < 10;
    int beg = off[wave];
    int end = off[wave + 1];
    float a0 = 0.f, a1 = 0.f, a2 = 0.f, a3 = 0.f;
    int e = beg + q;
    #define ACCUM40(P) { \
        a0 += bf2f_lo(P.x); a1 += bf2f_hi(P.x); \
        a2 += bf2f_lo(P.y); a3 += bf2f_hi(P.y); }
    for (; e + 4 < end; e += 8) {
        int s0 = srt[e];
        int s1 = srt[e + 4];
        if (act) {
            uint2 p0 = *(const uint2*)(p2b + (size_t)s0 * N_CLASS + l * 4);
            uint2 p1 = *(const uint2*)(p2b + (size_t)s1 * N_CLASS + l * 4);
            ACCUM40(p0)
            ACCUM40(p1)
        }
    }
    if (e < end && act) {
        int s0 = srt[e];
        uint2 p0 = *(const uint2*)(p2b + (size_t)s0 * N_CLASS + l * 4);
        ACCUM40(p0)
    }
    #undef ACCUM40
    #define RED(A) A += __shfl_xor(A, 16); A += __shfl_xor(A, 32);
    RED(a0) RED(a1) RED(a2) RED(a3)
    #undef RED
    if (lane < 10) {               // q==0, cols 4*lane..+3 < 40
        int c = end - beg;
        float inv = 1.0f / (float)(c > 1 ? c : 1);
        float4 rr = *(const float4*)(r2 + (size_t)wave * N_CLASS + lane * 4);
        float4 o;
        o.x = fmaf(a0, inv, rr.x);
        o.y = fmaf(a1, inv, rr.y);
        o.z = fmaf(a2, inv, rr.z);
        o.w = fmaf(a3, inv, rr.w);
        *(float4*)(outp + (size_t)wave * N_CLASS + lane * 4) = o;
    }
}

extern "C" void kernel_launch(void* const* d_in, const int* in_sizes, int n_in,
                              void* d_out, int out_size, void* d_ws, size_t ws_size,
                              hipStream_t stream) {
    const float* x   = (const float*)d_in[0];
    const int*   ei  = (const int*)d_in[1];   // [2][E] int32: row0=src, row1=dst
    const float* Wl1 = (const float*)d_in[2];
    const float* Wr1 = (const float*)d_in[3];
    const float* b1  = (const float*)d_in[4];
    const float* Wl2 = (const float*)d_in[5];
    const float* Wr2 = (const float*)d_in[6];
    const float* b2  = (const float*)d_in[7];
    float* out = (float*)d_out;

    const int N = in_sizes[0] / N_FEAT;       // 50000
    const int E = in_sizes[1] / 2;            // 800000
    const int* src = ei;
    const int* dst = ei + E;

    // Workspace carve. bins (8.4 MB) aliases p2b+r2 (12 MB): bins dead after
    // k_build; p2b/r2 first written in k_gemm12 (later).
    unsigned short* xb   = (unsigned short*)d_ws;            // N*128 bf16
    unsigned short* aggb = xb + (size_t)N * N_FEAT;          // N*128 bf16
    unsigned short* p2b  = aggb + (size_t)N * N_FEAT;        // N*40 bf16 (packed)
    float* r2 = (float*)(p2b + (size_t)N * N_CLASS);         // N*40 fp32
    uint2* bins = (uint2*)p2b;                               // NP*BCAP uint2 (alias)
    unsigned short* w1l  = (unsigned short*)(r2 + (size_t)N * N_CLASS);  // 16384
    unsigned short* w1r  = w1l + 16384;
    unsigned short* wc   = w1r + 16384;                      // 10240
    int* off = (int*)(wc + 10240);                           // N+1
    int* srt = off + N + 1;                                  // E
    int* ptail = srt + E;                                    // NP
    int* pbase = ptail + NP;                                 // NP

    const int TB = 256;
    int nCvt = (N * N_FEAT / 4 + TB - 1) / TB;               // 6250
    int bblocks = (E + BCHUNK - 1) / BCHUNK;                 // 196

    // 1. prep: cvt + swizzles + ptail zero
    k_prep<<<nCvt + 8 + 8 + 5 + 1, TB, 0, stream>>>(x, xb, nCvt, N * N_FEAT,
                                                    Wl1, Wr1, Wl2, Wr2,
                                                    w1l, w1r, wc, ptail);
    // 2-4. binned CSR build
    k_bin<<<bblocks, TB, 0, stream>>>(src, dst, ptail, bins, E);
    k_pscan<<<1, TB, 0, stream>>>(ptail, pbase, off, N);
    k_build<<<NP, TB, 0, stream>>>(bins, ptail, pbase, off, srt, N);

    int aggblocks = (N * 64 + TB - 1) / TB;   // one wave per node
    int gblocks = ((N + 15) / 16 + 3) / 4;    // 16 nodes/wave, 4 waves/block

    // 5. layer-1 aggregation
    k_aggb4<<<aggblocks, TB, 0, stream>>>(xb, srt, off, aggb, N);
    // 6. fused GEMM1 + layer-2 projection (h stays in LDS)
    k_gemm12<<<gblocks, TB, 0, stream>>>(aggb, xb, w1l, w1r, b1, wc, b2, p2b, r2, N);
    // 7. layer-2 aggregation + epilogue
    k_agg40<<<aggblocks, TB, 0, stream>>>(p2b, r2, srt, off, out, N);
}